// Round 5
// baseline (94.468 us; speedup 1.0000x reference)
//
#include <hip/hip_runtime.h>
#include <hip/hip_bf16.h>

#define TT 2048
#define CC 1024
#define HH 16
#define DD 64
#define FM 64
#define NCH 32
#define CL 64
#define N_QKV 3072
#define EPSV 1e-6f

// fp32 workspace region (float units)
#define OFF_KVT 0u          // KV^T fp32 [16][32][64d][64m]
#define OFF_KS  2097152u    // Ksum fp32 [16][32][64m]
#define OFF_Z   2129920u    // z fp32 [16][32][64m]
#define OFF_U16 2162688u    // bf16 region start (float units)
// bf16 region offsets (ushort units)
#define U_PROJT 0u          // projT bf16 [16][64m][64d]
#define U_VT  4194304u      // v^T bf16 [16][64][2048]
#define U_QP  6291456u      // q' bf16 [16][2048][64m]
#define U_KP  8388608u      // k' bf16 [16][2048][64m]
#define U_KPT 10485760u     // k'^T bf16 [16][64m][2048]
#define U_ST  12582912u     // S^T bf16 [16][32][64d][64m]
#define U_XBF 14680064u     // x bf16 (later aliased as attnb)
#define U_WQT 16777216u     // w_qkv^T bf16 [3072][1024]
#define U_WOT 19922944u     // w_out^T bf16 [1024][1024]

typedef __attribute__((ext_vector_type(8))) short bf16x8;
typedef __attribute__((ext_vector_type(4))) float f32x4;
typedef __attribute__((ext_vector_type(4))) unsigned short u16x4;

__device__ __forceinline__ unsigned short f2bf(float f) {
  unsigned int u = __float_as_uint(f);
  u = (u + 0x7fffu + ((u >> 16) & 1u)) >> 16;
  return (unsigned short)u;
}
__device__ __forceinline__ float bf2f(unsigned short b) {
  return __uint_as_float(((unsigned)b) << 16);
}

__device__ __forceinline__ void gload16(const void* g, void* l) {
  __builtin_amdgcn_global_load_lds(
      (const __attribute__((address_space(1))) unsigned int*)g,
      (__attribute__((address_space(3))) unsigned int*)l, 16, 0, 0);
}

// stage a 64-row x 64-ushort (8KB) tile into LDS, XOR-swizzled (chunk^=row&7)
__device__ __forceinline__ void stage_tile64(const unsigned short* g, unsigned rowstride,
                                             unsigned short* lds, int w, int lane) {
  const int l8 = lane >> 3, l7 = lane & 7;
  const int kcg = (l7 ^ l8) * 8;
#pragma unroll
  for (int jj = 0; jj < 2; ++jj) {
    const int inst = w * 2 + jj;
    const int row = inst * 8 + l8;
    gload16(&g[(unsigned)row * rowstride + kcg], &lds[inst * 512]);
  }
}

// read an 8-element bf16 fragment from a swizzled 64x64 LDS tile
__device__ __forceinline__ bf16x8 frag64(const unsigned short* lds, int r, int kchunk) {
  const int slot = kchunk ^ (r & 7);
  return *reinterpret_cast<const bf16x8*>(&lds[r * 64 + slot * 8]);
}

// ---------------- Kernel 0: fused prep (xconv + 2 transposes + projT) ------
__device__ __forceinline__ void transpose64_dev(const float* __restrict__ src,
                                                unsigned short* __restrict__ dst,
                                                int K, int N, int k0, int n0,
                                                float (*T)[68], int tid) {
#pragma unroll
  for (int it = 0; it < 4; ++it) {
    int f = tid + it * 256;
    int r = f >> 4, c4 = (f & 15) * 4;
    float4 v = *reinterpret_cast<const float4*>(&src[(unsigned)(k0 + r) * N + n0 + c4]);
    T[r][c4 + 0] = v.x; T[r][c4 + 1] = v.y;
    T[r][c4 + 2] = v.z; T[r][c4 + 3] = v.w;
  }
  __syncthreads();
#pragma unroll
  for (int it = 0; it < 4; ++it) {
    int f = tid + it * 256;
    int nl = f >> 4, kq = (f & 15) * 4;
    u16x4 o;
#pragma unroll
    for (int j = 0; j < 4; ++j) o[j] = f2bf(T[kq + j][nl]);
    *reinterpret_cast<u16x4*>(&dst[(unsigned)(n0 + nl) * K + k0 + kq]) = o;
  }
}

__global__ __launch_bounds__(256) void k_prep(const float* __restrict__ x,
                                              const float* __restrict__ wq,
                                              const float* __restrict__ wo,
                                              const float* __restrict__ proj,
                                              unsigned short* __restrict__ xbf,
                                              unsigned short* __restrict__ wqT,
                                              unsigned short* __restrict__ woT,
                                              unsigned short* __restrict__ projT) {
  __shared__ float T[64][68];
  const int tid = threadIdx.x;
  int b = blockIdx.x;
  if (b < 2048) {  // x f32 -> bf16
    unsigned i = (unsigned)b * 1024u + (unsigned)tid * 4u;
    float4 v = *reinterpret_cast<const float4*>(&x[i]);
    u16x4 o;
    o[0] = f2bf(v.x); o[1] = f2bf(v.y); o[2] = f2bf(v.z); o[3] = f2bf(v.w);
    *reinterpret_cast<u16x4*>(&xbf[i]) = o;
    return;
  }
  b -= 2048;
  if (b < 768) {  // w_qkv [1024][3072] -> wqT [3072][1024]
    transpose64_dev(wq, wqT, CC, N_QKV, (b / 48) * 64, (b % 48) * 64, T, tid);
    return;
  }
  b -= 768;
  if (b < 256) {  // w_out [1024][1024] -> woT [1024][1024]
    transpose64_dev(wo, woT, CC, CC, (b / 16) * 64, (b % 16) * 64, T, tid);
    return;
  }
  b -= 256;  // proj [h][64d][64m] -> projT [h][64m][64d]
  transpose64_dev(proj + (unsigned)b * 4096u, projT + (unsigned)b * 4096u, 64, 64, 0, 0, T, tid);
}

// ---------------- shared 128x128 MFMA GEMM core ----------------------------
__device__ __forceinline__ void gemm_core_128(
    const unsigned short* __restrict__ A, const unsigned short* __restrict__ BT,
    int K, int m0, int n0, unsigned short* As, unsigned short* Bs,
    f32x4 acc[4][4]) {
  const int tid = threadIdx.x;
  const int lane = tid & 63;
  const int w = tid >> 6;
  const int wm = w >> 1, wn = w & 1;
  const int l8 = lane >> 3, l7 = lane & 7;
  const int kcg = (l7 ^ l8) * 8;
  for (int k0 = 0; k0 < K; k0 += 64) {
    if (k0) __syncthreads();
#pragma unroll
    for (int j = 0; j < 4; ++j) {
      const int inst = w * 4 + j;
      const int row = inst * 8 + l8;
      gload16(&A[(unsigned)(m0 + row) * K + k0 + kcg], &As[inst * 512]);
      gload16(&BT[(unsigned)(n0 + row) * K + k0 + kcg], &Bs[inst * 512]);
    }
    __syncthreads();
#pragma unroll
    for (int kk = 0; kk < 2; ++kk) {
      bf16x8 af[4], bg[4];
#pragma unroll
      for (int i = 0; i < 4; ++i) {
        const int r = wm * 64 + i * 16 + (lane & 15);
        const int slot = (kk * 4 + (lane >> 4)) ^ (r & 7);
        af[i] = *reinterpret_cast<const bf16x8*>(&As[r * 64 + slot * 8]);
      }
#pragma unroll
      for (int j = 0; j < 4; ++j) {
        const int r = wn * 64 + j * 16 + (lane & 15);
        const int slot = (kk * 4 + (lane >> 4)) ^ (r & 7);
        bg[j] = *reinterpret_cast<const bf16x8*>(&Bs[r * 64 + slot * 8]);
      }
#pragma unroll
      for (int i = 0; i < 4; ++i)
#pragma unroll
        for (int j = 0; j < 4; ++j)
          acc[i][j] = __builtin_amdgcn_mfma_f32_16x16x32_bf16(af[i], bg[j],
                                                              acc[i][j], 0, 0, 0);
    }
  }
}

// ---------------- Kernel 1: fused QKV GEMM + feature map -------------------
// q/k blocks: per-warp 64t x 64d tile -> p' = relu(q@projT)/8 in-kernel,
// write q'/k' [h][t][m] coalesced (+ ksum, k'T for k). v blocks: write vT.
__global__ __launch_bounds__(256) void k_qkvf(const unsigned short* __restrict__ Xbf,
                                              const unsigned short* __restrict__ WqT,
                                              const float* __restrict__ bias,
                                              const unsigned short* __restrict__ projT,
                                              unsigned short* __restrict__ vt,
                                              unsigned short* __restrict__ qp,
                                              unsigned short* __restrict__ kp,
                                              unsigned short* __restrict__ kpt,
                                              float* __restrict__ ksum) {
  __shared__ unsigned short LDSU[16384];  // GEMM: As|Bs; after: 8KB/warp quadrants
  f32x4 acc[4][4] = {};
  gemm_core_128(Xbf, WqT, CC, blockIdx.y * 128, blockIdx.x * 128, LDSU, LDSU + 8192, acc);
  const int tid = threadIdx.x, lane = tid & 63, w = tid >> 6;
  const int wm = w >> 1, wn = w & 1;
  const int n0w = blockIdx.x * 128 + wn * 64;
  const int sel = n0w >> 10;                 // uniform per block
  const int h = (n0w & 1023) >> 6;
  const int t0g = blockIdx.y * 128 + wm * 64;
  float bvj[4];
#pragma unroll
  for (int j = 0; j < 4; ++j) bvj[j] = bias[n0w + j * 16 + (lane & 15)];
  __syncthreads();  // all MFMA reads of LDSU done
  if (sel == 2) {
    // v: write vT [h][d][t] directly (u16x4 along t)
#pragma unroll
    for (int i = 0; i < 4; ++i) {
      const int tl = i * 16 + (lane >> 4) * 4;
#pragma unroll
      for (int j = 0; j < 4; ++j) {
        const int d = j * 16 + (lane & 15);
        u16x4 o;
#pragma unroll
        for (int r = 0; r < 4; ++r) o[r] = f2bf(acc[i][j][r] + bvj[j]);
        *reinterpret_cast<u16x4*>(&vt[((unsigned)h * 64 + d) * TT + t0g + tl]) = o;
      }
    }
    return;
  }
  // q/k: stage tile into warp-private LDS quadrant as [t][d] swizzled
  unsigned short* myT = &LDSU[w * 4096];
#pragma unroll
  for (int i = 0; i < 4; ++i)
#pragma unroll
    for (int j = 0; j < 4; ++j) {
      const int d = j * 16 + (lane & 15);
#pragma unroll
      for (int r = 0; r < 4; ++r) {
        const int tl = i * 16 + (lane >> 4) * 4 + r;
        myT[tl * 64 + (((d >> 3) ^ (tl & 7)) << 3) + (d & 7)] = f2bf(acc[i][j][r] + bvj[j]);
      }
    }
  // A-frags (rows t, k=d) from LDS; B-frags (rows m, k=d) straight from projT global
  bf16x8 aq[4][2], bp[4][2];
#pragma unroll
  for (int i = 0; i < 4; ++i)
#pragma unroll
    for (int kk = 0; kk < 2; ++kk)
      aq[i][kk] = frag64(myT, i * 16 + (lane & 15), kk * 4 + (lane >> 4));
  const unsigned short* pjt = projT + (unsigned)h * 4096u;
#pragma unroll
  for (int jm = 0; jm < 4; ++jm)
#pragma unroll
    for (int kk = 0; kk < 2; ++kk)
      bp[jm][kk] = *reinterpret_cast<const bf16x8*>(
          &pjt[(unsigned)(jm * 16 + (lane & 15)) * 64 + kk * 32 + (lane >> 4) * 8]);
  f32x4 accp[4][4] = {};
#pragma unroll
  for (int i = 0; i < 4; ++i)
#pragma unroll
    for (int jm = 0; jm < 4; ++jm)
#pragma unroll
      for (int kk = 0; kk < 2; ++kk)
        accp[i][jm] = __builtin_amdgcn_mfma_f32_16x16x32_bf16(aq[i][kk], bp[jm][kk],
                                                              accp[i][jm], 0, 0, 0);
#pragma unroll
  for (int i = 0; i < 4; ++i)
#pragma unroll
    for (int jm = 0; jm < 4; ++jm)
#pragma unroll
      for (int r = 0; r < 4; ++r) {
        float v = accp[i][jm][r];
        accp[i][jm][r] = (v > 0.f ? v : 0.f) * 0.125f;
      }
  // overwrite myT with p' [t][m] swizzled
#pragma unroll
  for (int i = 0; i < 4; ++i)
#pragma unroll
    for (int jm = 0; jm < 4; ++jm) {
      const int m = jm * 16 + (lane & 15);
#pragma unroll
      for (int r = 0; r < 4; ++r) {
        const int tl = i * 16 + (lane >> 4) * 4 + r;
        myT[tl * 64 + (((m >> 3) ^ (tl & 7)) << 3) + (m & 7)] = f2bf(accp[i][jm][r]);
      }
    }
  // coalesced store of p' rows to qp/kp [h][t][m]
  unsigned short* dstq = (sel ? kp : qp) + ((unsigned)h * TT + (unsigned)t0g) * 64u;
#pragma unroll
  for (int rep = 0; rep < 8; ++rep) {
    const int cid = rep * 64 + lane;
    const int tl = cid >> 3, cc = cid & 7;
    bf16x8 vv = *reinterpret_cast<const bf16x8*>(&myT[tl * 64 + ((cc ^ (tl & 7)) << 3)]);
    *reinterpret_cast<bf16x8*>(&dstq[(unsigned)tl * 64 + cc * 8]) = vv;
  }
  if (sel == 1) {
    const int c = blockIdx.y * 2 + wm;  // this warp's chunk
    // ksum[m] = sum_t p'[t][m]
#pragma unroll
    for (int jm = 0; jm < 4; ++jm) {
      float s = 0.f;
#pragma unroll
      for (int i = 0; i < 4; ++i)
#pragma unroll
        for (int r = 0; r < 4; ++r) s += accp[i][jm][r];
      s += __shfl_xor(s, 16, 64);
      s += __shfl_xor(s, 32, 64);
      if (lane < 16) ksum[((unsigned)h * NCH + c) * 64u + jm * 16 + lane] = s;
    }
    // k'T [h][m][t]: lane = m, assemble 8-t chunks from LDS
    unsigned short* kd = kpt + ((unsigned)h * 64 + lane) * TT + t0g;
#pragma unroll
    for (int tc = 0; tc < 8; ++tc) {
      bf16x8 tv;
#pragma unroll
      for (int e = 0; e < 8; ++e) {
        const int t = tc * 8 + e;
        tv[e] = (short)myT[t * 64 + (((lane >> 3) ^ (t & 7)) << 3) + (lane & 7)];
      }
      *reinterpret_cast<bf16x8*>(&kd[tc * 8]) = tv;
    }
  }
}

// ---------------- Kernel 3: KV^T[d][m] = sum_t k'[t][m] v[t][d] (MFMA) -----
__global__ __launch_bounds__(256) void k_chunkkv(const unsigned short* __restrict__ kpt,
                                                 const unsigned short* __restrict__ vt,
                                                 float* __restrict__ kvt) {
  __shared__ unsigned short KTs[4096];
  __shared__ unsigned short VTs[4096];
  const int tid = threadIdx.x, lane = tid & 63, w = tid >> 6;
  const int c = blockIdx.x, h = blockIdx.y;
  stage_tile64(kpt + (unsigned)h * 64 * TT + (unsigned)c * 64, TT, KTs, w, lane);
  stage_tile64(vt + (unsigned)h * 64 * TT + (unsigned)c * 64, TT, VTs, w, lane);
  __syncthreads();
  const int mr = w * 16 + (lane & 15);
  bf16x8 af[2];
#pragma unroll
  for (int kk = 0; kk < 2; ++kk) af[kk] = frag64(KTs, mr, kk * 4 + (lane >> 4));
  f32x4 acc[4] = {};
#pragma unroll
  for (int j = 0; j < 4; ++j)
#pragma unroll
    for (int kk = 0; kk < 2; ++kk)
      acc[j] = __builtin_amdgcn_mfma_f32_16x16x32_bf16(
          af[kk], frag64(VTs, j * 16 + (lane & 15), kk * 4 + (lane >> 4)), acc[j], 0, 0, 0);
  float* dst = kvt + ((unsigned)h * NCH + c) * 4096u;
#pragma unroll
  for (int j = 0; j < 4; ++j) {
    const int d = j * 16 + (lane & 15);
    const int mq = w * 16 + (lane >> 4) * 4;
    *reinterpret_cast<f32x4*>(&dst[(unsigned)d * 64 + mq]) = acc[j];
  }
}

// ---------------- Kernel 4: exclusive prefix over chunks (parallel) --------
__global__ __launch_bounds__(256) void k_prefix(const float* __restrict__ kvt,
                                                const float* __restrict__ ksum,
                                                unsigned short* __restrict__ st,
                                                float* __restrict__ z) {
  const int h = blockIdx.y;
  const unsigned e = blockIdx.x * 256u + threadIdx.x;
  float run = 0.f;
#pragma unroll
  for (int c = 0; c < NCH; ++c) {
    const unsigned idx = ((unsigned)h * NCH + c) * 4096u + e;
    st[idx] = f2bf(run);
    run += kvt[idx];
  }
  if (blockIdx.x == 0 && threadIdx.x < 64) {
    float zr = 0.f;
#pragma unroll
    for (int c = 0; c < NCH; ++c) {
      const unsigned idx = ((unsigned)h * NCH + c) * 64u + threadIdx.x;
      z[idx] = zr;
      zr += ksum[idx];
    }
  }
}

// ---------------- Kernel 5: per-(h,c) intra-chunk attention (MFMA) ---------
__global__ __launch_bounds__(256) void k_attn(const unsigned short* __restrict__ qp,
                                              const unsigned short* __restrict__ kp,
                                              const unsigned short* __restrict__ vt,
                                              const unsigned short* __restrict__ st,
                                              const float* __restrict__ z,
                                              unsigned short* __restrict__ attnb) {
  __shared__ unsigned short QPs[4096];
  __shared__ unsigned short KPs[4096];  // reused as A^bf16 after phase A
  __shared__ unsigned short VTs[4096];
  __shared__ unsigned short STs[4096];
  __shared__ float zsm[64];
  __shared__ float nsm[64];
  const int tid = threadIdx.x, lane = tid & 63, w = tid >> 6;
  const int c = blockIdx.x, h = blockIdx.y;
  stage_tile64(qp + ((unsigned)h * TT + c * 64) * 64, 64, QPs, w, lane);
  stage_tile64(kp + ((unsigned)h * TT + c * 64) * 64, 64, KPs, w, lane);
  stage_tile64(vt + (unsigned)h * 64 * TT + (unsigned)c * 64, TT, VTs, w, lane);
  stage_tile64(st + ((unsigned)h * NCH + c) * 4096u, 64, STs, w, lane);
  if (tid < 64) zsm[tid] = z[((unsigned)h * NCH + c) * 64u + tid];
  __syncthreads();
  const int tr = w * 16 + (lane & 15);
  bf16x8 afq[2];
#pragma unroll
  for (int kk = 0; kk < 2; ++kk) afq[kk] = frag64(QPs, tr, kk * 4 + (lane >> 4));
  f32x4 accA[4] = {};
#pragma unroll
  for (int j = 0; j < 4; ++j)
#pragma unroll
    for (int kk = 0; kk < 2; ++kk)
      accA[j] = __builtin_amdgcn_mfma_f32_16x16x32_bf16(
          afq[kk], frag64(KPs, j * 16 + (lane & 15), kk * 4 + (lane >> 4)), accA[j], 0, 0, 0);
  float rs[4] = {0.f, 0.f, 0.f, 0.f};
#pragma unroll
  for (int j = 0; j < 4; ++j) {
    const int s = j * 16 + (lane & 15);
#pragma unroll
    for (int r = 0; r < 4; ++r) {
      const int t = w * 16 + (lane >> 4) * 4 + r;
      float v = (s <= t) ? accA[j][r] : 0.f;
      accA[j][r] = v;
      rs[r] += v;
    }
  }
#pragma unroll
  for (int r = 0; r < 4; ++r)
#pragma unroll
    for (int off = 1; off < 16; off <<= 1) rs[r] += __shfl_xor(rs[r], off, 64);
  __syncthreads();
  if ((lane & 15) == 0) {
#pragma unroll
    for (int r = 0; r < 4; ++r) nsm[w * 16 + (lane >> 4) * 4 + r] = rs[r];
  }
#pragma unroll
  for (int j = 0; j < 4; ++j) {
    const int s = j * 16 + (lane & 15);
#pragma unroll
    for (int r = 0; r < 4; ++r) {
      const int t = w * 16 + (lane >> 4) * 4 + r;
      KPs[t * 64 + (((s >> 3) ^ (t & 7)) * 8) + (s & 7)] = f2bf(accA[j][r]);
    }
  }
  __syncthreads();
  {
    const int t = tid >> 2, part = tid & 3;
    float qz = 0.f;
#pragma unroll
    for (int mm = 0; mm < 16; ++mm) {
      const int m = part * 16 + mm;
      qz += bf2f(QPs[t * 64 + (((m >> 3) ^ (t & 7)) * 8) + (m & 7)]) * zsm[m];
    }
    qz += __shfl_xor(qz, 1, 64);
    qz += __shfl_xor(qz, 2, 64);
    if (part == 0) nsm[t] += qz + EPSV;
  }
  bf16x8 afa[2];
#pragma unroll
  for (int kk = 0; kk < 2; ++kk) afa[kk] = frag64(KPs, tr, kk * 4 + (lane >> 4));
  f32x4 acc[4] = {};
#pragma unroll
  for (int j = 0; j < 4; ++j) {
    const int br = j * 16 + (lane & 15);
#pragma unroll
    for (int kk = 0; kk < 2; ++kk) {
      acc[j] = __builtin_amdgcn_mfma_f32_16x16x32_bf16(
          afa[kk], frag64(VTs, br, kk * 4 + (lane >> 4)), acc[j], 0, 0, 0);
      acc[j] = __builtin_amdgcn_mfma_f32_16x16x32_bf16(
          afq[kk], frag64(STs, br, kk * 4 + (lane >> 4)), acc[j], 0, 0, 0);
    }
  }
  __syncthreads();
#pragma unroll
  for (int j = 0; j < 4; ++j) {
    const int d = j * 16 + (lane & 15);
#pragma unroll
    for (int r = 0; r < 4; ++r) {
      const int t = w * 16 + (lane >> 4) * 4 + r;
      attnb[(unsigned)(c * 64 + t) * CC + h * 64 + d] = f2bf(acc[j][r] / nsm[t]);
    }
  }
}

// ---------------- Kernel 6: out = attn @ w_out + b (128x64 tiles) ----------
__global__ __launch_bounds__(256) void k_out_mfma(const unsigned short* __restrict__ Abf,
                                                  const unsigned short* __restrict__ WoT,
                                                  const float* __restrict__ bias,
                                                  float* __restrict__ out) {
  __shared__ unsigned short As[8192];  // 128 x 64
  __shared__ unsigned short Bs[4096];  // 64 x 64
  const int tid = threadIdx.x, lane = tid & 63, w = tid >> 6;
  const int wm = w >> 1, wn = w & 1;
  const int m0 = blockIdx.y * 128, n0 = blockIdx.x * 64;
  const int l8 = lane >> 3, l7 = lane & 7;
  const int kcg = (l7 ^ l8) * 8;
  f32x4 acc[4][2] = {};
  for (int k0 = 0; k0 < CC; k0 += 64) {
    if (k0) __syncthreads();
#pragma unroll
    for (int j = 0; j < 4; ++j) {
      const int inst = w * 4 + j;
      const int row = inst * 8 + l8;
      gload16(&Abf[(unsigned)(m0 + row) * CC + k0 + kcg], &As[inst * 512]);
    }
#pragma unroll
    for (int jj = 0; jj < 2; ++jj) {
      const int inst = w * 2 + jj;
      const int row = inst * 8 + l8;
      gload16(&WoT[(unsigned)(n0 + row) * CC + k0 + kcg], &Bs[inst * 512]);
    }
    __syncthreads();
#pragma unroll
    for (int kk = 0; kk < 2; ++kk) {
      bf16x8 af[4], bg[2];
#pragma unroll
      for (int i = 0; i < 4; ++i) {
        const int r = wm * 64 + i * 16 + (lane & 15);
        const int slot = (kk * 4 + (lane >> 4)) ^ (r & 7);
        af[i] = *reinterpret_cast<const bf16x8*>(&As[r * 64 + slot * 8]);
      }
#pragma unroll
      for (int j = 0; j < 2; ++j) {
        const int r = wn * 32 + j * 16 + (lane & 15);
        const int slot = (kk * 4 + (lane >> 4)) ^ (r & 7);
        bg[j] = *reinterpret_cast<const bf16x8*>(&Bs[r * 64 + slot * 8]);
      }
#pragma unroll
      for (int i = 0; i < 4; ++i)
#pragma unroll
        for (int j = 0; j < 2; ++j)
          acc[i][j] = __builtin_amdgcn_mfma_f32_16x16x32_bf16(af[i], bg[j],
                                                              acc[i][j], 0, 0, 0);
    }
  }
#pragma unroll
  for (int i = 0; i < 4; ++i) {
#pragma unroll
    for (int j = 0; j < 2; ++j) {
      const int n = n0 + wn * 32 + j * 16 + (lane & 15);
      const float bv = bias[n];
#pragma unroll
      for (int r = 0; r < 4; ++r) {
        const int m = m0 + wm * 64 + i * 16 + (lane >> 4) * 4 + r;
        out[(unsigned)m * CC + n] = acc[i][j][r] + bv;
      }
    }
  }
}

extern "C" void kernel_launch(void* const* d_in, const int* in_sizes, int n_in,
                              void* d_out, int out_size, void* d_ws, size_t ws_size,
                              hipStream_t stream) {
  const float* x = (const float*)d_in[0];
  const float* w_qkv = (const float*)d_in[1];
  const float* b_qkv = (const float*)d_in[2];
  const float* w_out = (const float*)d_in[3];
  const float* b_out = (const float*)d_in[4];
  const float* proj = (const float*)d_in[5];
  float* ws = (float*)d_ws;
  float* out = (float*)d_out;
  float* kvt = ws + OFF_KVT;
  float* ksum = ws + OFF_KS;
  float* zf = ws + OFF_Z;
  unsigned short* ub = (unsigned short*)(ws + OFF_U16);
  unsigned short* projT = ub + U_PROJT;
  unsigned short* vt = ub + U_VT;
  unsigned short* qp = ub + U_QP;
  unsigned short* kp = ub + U_KP;
  unsigned short* kpt = ub + U_KPT;
  unsigned short* st = ub + U_ST;
  unsigned short* xbf = ub + U_XBF;
  unsigned short* wqT = ub + U_WQT;
  unsigned short* woT = ub + U_WOT;
  unsigned short* attnb = xbf;  // alias: x_bf16 dead after k_qkvf
  dim3 blk(256, 1, 1);
  k_prep<<<dim3(3088), blk, 0, stream>>>(x, w_qkv, w_out, proj, xbf, wqT, woT, projT);
  k_qkvf<<<dim3(N_QKV / 128, TT / 128), blk, 0, stream>>>(xbf, wqT, b_qkv, projT,
                                                          vt, qp, kp, kpt, ksum);
  k_chunkkv<<<dim3(NCH, HH), blk, 0, stream>>>(kpt, vt, kvt);
  k_prefix<<<dim3(16, HH), blk, 0, stream>>>(kvt, ksum, st, zf);
  k_attn<<<dim3(NCH, HH), blk, 0, stream>>>(qp, kp, vt, st, zf, attnb);
  k_out_mfma<<<dim3(CC / 64, TT / 128), blk, 0, stream>>>(attnb, woT, b_out, out);
}

// Round 6
// 78.403 us; speedup vs baseline: 1.2049x; 1.2049x over previous
//
#include <hip/hip_runtime.h>
#include <hip/hip_bf16.h>

#define TT 2048
#define CC 1024
#define HH 16
#define DD 64
#define FM 64
#define NCH 32
#define CL 64
#define N_QKV 3072
#define EPSV 1e-6f

// fp32 workspace region (float units)
#define OFF_KVT 0u          // KV^T fp32 [16][32][64d][64m]
#define OFF_KS  2097152u    // Ksum fp32 [16][32][64m]
#define OFF_Z   2129920u    // z fp32 [16][32][64m]
#define OFF_U16 2162688u    // bf16 region start (float units)
// bf16 region offsets (ushort units)
#define U_QBF 0u            // q bf16 [16][2048][64]
#define U_KBF 2097152u      // k bf16 [16][2048][64]
#define U_VT  4194304u      // v^T bf16 [16][64][2048]
#define U_QP  6291456u      // q' bf16 [16][2048][64m]
#define U_KP  8388608u      // k' bf16 [16][2048][64m]
#define U_ST  12582912u     // S^T bf16 [16][32][64d][64m]
#define U_XBF 14680064u     // x bf16 (later aliased as attnb)
#define U_WQT 16777216u     // w_qkv^T bf16 [3072][1024]
#define U_WOT 19922944u     // w_out^T bf16 [1024][1024]

typedef __attribute__((ext_vector_type(8))) short bf16x8;
typedef __attribute__((ext_vector_type(4))) float f32x4;
typedef __attribute__((ext_vector_type(4))) unsigned short u16x4;

__device__ __forceinline__ unsigned short f2bf(float f) {
  unsigned int u = __float_as_uint(f);
  u = (u + 0x7fffu + ((u >> 16) & 1u)) >> 16;
  return (unsigned short)u;
}
__device__ __forceinline__ float bf2f(unsigned short b) {
  return __uint_as_float(((unsigned)b) << 16);
}

__device__ __forceinline__ void gload16(const void* g, void* l) {
  __builtin_amdgcn_global_load_lds(
      (const __attribute__((address_space(1))) unsigned int*)g,
      (__attribute__((address_space(3))) unsigned int*)l, 16, 0, 0);
}

// stage a 64-row x 64-ushort (8KB) tile into LDS, XOR-swizzled (chunk^=row&7)
__device__ __forceinline__ void stage_tile64(const unsigned short* g, unsigned rowstride,
                                             unsigned short* lds, int w, int lane) {
  const int l8 = lane >> 3, l7 = lane & 7;
  const int kcg = (l7 ^ l8) * 8;
#pragma unroll
  for (int jj = 0; jj < 2; ++jj) {
    const int inst = w * 2 + jj;
    const int row = inst * 8 + l8;
    gload16(&g[(unsigned)row * rowstride + kcg], &lds[inst * 512]);
  }
}

// read an 8-element bf16 fragment from a swizzled 64x64 LDS tile
__device__ __forceinline__ bf16x8 frag64(const unsigned short* lds, int r, int kchunk) {
  const int slot = kchunk ^ (r & 7);
  return *reinterpret_cast<const bf16x8*>(&lds[r * 64 + slot * 8]);
}

// ---------------- Kernel 0: fused prep (xconv + 2 weight transposes) -------
__device__ __forceinline__ void transpose64_dev(const float* __restrict__ src,
                                                unsigned short* __restrict__ dst,
                                                int K, int N, int k0, int n0,
                                                float (*T)[68], int tid) {
#pragma unroll
  for (int it = 0; it < 4; ++it) {
    int f = tid + it * 256;
    int r = f >> 4, c4 = (f & 15) * 4;
    float4 v = *reinterpret_cast<const float4*>(&src[(unsigned)(k0 + r) * N + n0 + c4]);
    T[r][c4 + 0] = v.x; T[r][c4 + 1] = v.y;
    T[r][c4 + 2] = v.z; T[r][c4 + 3] = v.w;
  }
  __syncthreads();
#pragma unroll
  for (int it = 0; it < 4; ++it) {
    int f = tid + it * 256;
    int nl = f >> 4, kq = (f & 15) * 4;
    u16x4 o;
#pragma unroll
    for (int j = 0; j < 4; ++j) o[j] = f2bf(T[kq + j][nl]);
    *reinterpret_cast<u16x4*>(&dst[(unsigned)(n0 + nl) * K + k0 + kq]) = o;
  }
}

__global__ __launch_bounds__(256) void k_prep(const float* __restrict__ x,
                                              const float* __restrict__ wq,
                                              const float* __restrict__ wo,
                                              unsigned short* __restrict__ xbf,
                                              unsigned short* __restrict__ wqT,
                                              unsigned short* __restrict__ woT) {
  __shared__ float T[64][68];
  const int tid = threadIdx.x;
  int b = blockIdx.x;
  if (b < 2048) {  // x f32 -> bf16
    unsigned i = (unsigned)b * 1024u + (unsigned)tid * 4u;
    float4 v = *reinterpret_cast<const float4*>(&x[i]);
    u16x4 o;
    o[0] = f2bf(v.x); o[1] = f2bf(v.y); o[2] = f2bf(v.z); o[3] = f2bf(v.w);
    *reinterpret_cast<u16x4*>(&xbf[i]) = o;
    return;
  }
  b -= 2048;
  if (b < 768) {  // w_qkv [1024][3072] -> wqT [3072][1024]
    transpose64_dev(wq, wqT, CC, N_QKV, (b / 48) * 64, (b % 48) * 64, T, tid);
    return;
  }
  b -= 768;  // w_out [1024][1024] -> woT [1024][1024]
  transpose64_dev(wo, woT, CC, CC, (b / 16) * 64, (b % 16) * 64, T, tid);
}

// ---------------- shared 128x128 MFMA GEMM core ----------------------------
__device__ __forceinline__ void gemm_core_128(
    const unsigned short* __restrict__ A, const unsigned short* __restrict__ BT,
    int K, int m0, int n0, unsigned short* As, unsigned short* Bs,
    f32x4 acc[4][4]) {
  const int tid = threadIdx.x;
  const int lane = tid & 63;
  const int w = tid >> 6;
  const int wm = w >> 1, wn = w & 1;
  const int l8 = lane >> 3, l7 = lane & 7;
  const int kcg = (l7 ^ l8) * 8;
  for (int k0 = 0; k0 < K; k0 += 64) {
    if (k0) __syncthreads();
#pragma unroll
    for (int j = 0; j < 4; ++j) {
      const int inst = w * 4 + j;
      const int row = inst * 8 + l8;
      gload16(&A[(unsigned)(m0 + row) * K + k0 + kcg], &As[inst * 512]);
      gload16(&BT[(unsigned)(n0 + row) * K + k0 + kcg], &Bs[inst * 512]);
    }
    __syncthreads();
#pragma unroll
    for (int kk = 0; kk < 2; ++kk) {
      bf16x8 af[4], bg[4];
#pragma unroll
      for (int i = 0; i < 4; ++i) {
        const int r = wm * 64 + i * 16 + (lane & 15);
        const int slot = (kk * 4 + (lane >> 4)) ^ (r & 7);
        af[i] = *reinterpret_cast<const bf16x8*>(&As[r * 64 + slot * 8]);
      }
#pragma unroll
      for (int j = 0; j < 4; ++j) {
        const int r = wn * 64 + j * 16 + (lane & 15);
        const int slot = (kk * 4 + (lane >> 4)) ^ (r & 7);
        bg[j] = *reinterpret_cast<const bf16x8*>(&Bs[r * 64 + slot * 8]);
      }
#pragma unroll
      for (int i = 0; i < 4; ++i)
#pragma unroll
        for (int j = 0; j < 4; ++j)
          acc[i][j] = __builtin_amdgcn_mfma_f32_16x16x32_bf16(af[i], bg[j],
                                                              acc[i][j], 0, 0, 0);
    }
  }
}

// ---------------- Kernel 1: qkv GEMM, scatter q/k bf16, vT bf16 ------------
__global__ __launch_bounds__(256) void k_qkv_mfma(const unsigned short* __restrict__ Xbf,
                                                  const unsigned short* __restrict__ WqT,
                                                  const float* __restrict__ bias,
                                                  unsigned short* __restrict__ qbf,
                                                  unsigned short* __restrict__ kbf,
                                                  unsigned short* __restrict__ vt) {
  __shared__ unsigned short As[128 * 64];
  __shared__ unsigned short Bs[128 * 64];
  // XCD-aware bijective swizzle (nwg = 384, 384%8==0)
  int lin = blockIdx.y * 24 + blockIdx.x;
  int swz = (lin & 7) * 48 + (lin >> 3);
  const int bx = swz % 24, by = swz / 24;
  f32x4 acc[4][4] = {};
  gemm_core_128(Xbf, WqT, CC, by * 128, bx * 128, As, Bs, acc);
  const int lane = threadIdx.x & 63, w = threadIdx.x >> 6;
  const int m0 = by * 128 + (w >> 1) * 64;
  const int n0 = bx * 128 + (w & 1) * 64;
#pragma unroll
  for (int i = 0; i < 4; ++i) {
    const int t0 = m0 + i * 16 + (lane >> 4) * 4;
#pragma unroll
    for (int j = 0; j < 4; ++j) {
      const int n = n0 + j * 16 + (lane & 15);
      const float bv = bias[n];
      const int sel = n >> 10, within = n & 1023;
      const int h = within >> 6, d = within & 63;
      if (sel == 2) {
        u16x4 o;
#pragma unroll
        for (int r = 0; r < 4; ++r) o[r] = f2bf(acc[i][j][r] + bv);
        *reinterpret_cast<u16x4*>(&vt[((unsigned)h * 64 + d) * TT + t0]) = o;
      } else {
        unsigned short* dst = (sel ? kbf : qbf) + (unsigned)h * TT * 64 + d;
#pragma unroll
        for (int r = 0; r < 4; ++r)
          dst[(unsigned)(t0 + r) * 64] = f2bf(acc[i][j][r] + bv);
      }
    }
  }
}

// ---------------- Kernel 2: MFMA feature map + fused per-chunk KV ----------
// p^T[m][t] = sum_d proj[d][m] x[t][d]; relu/8; writes q'/k' [t][m];
// for k (which==1): also KV^T[d][m] = sum_t k'[t][m] v[t][d]  and Ksum[m].
__global__ __launch_bounds__(256) void k_feat(const float* __restrict__ proj,
                                              const unsigned short* __restrict__ qbf,
                                              const unsigned short* __restrict__ kbf,
                                              const unsigned short* __restrict__ vt,
                                              unsigned short* __restrict__ qp,
                                              unsigned short* __restrict__ kp,
                                              float* __restrict__ kvt,
                                              float* __restrict__ ksum) {
  __shared__ unsigned short Xs[4096];
  __shared__ float Pj[4096];
  __shared__ unsigned short Os[4096];
  __shared__ unsigned short VTs[4096];
  const int tid = threadIdx.x, lane = tid & 63, w = tid >> 6;
  const int c = blockIdx.x, h = blockIdx.y, which = blockIdx.z;
  const unsigned short* src = (which ? kbf : qbf) + ((unsigned)h * TT + c * 64) * 64;
  stage_tile64(src, 64, Xs, w, lane);
  if (which) stage_tile64(vt + (unsigned)h * 64 * TT + (unsigned)c * 64, TT, VTs, w, lane);
#pragma unroll
  for (int it = 0; it < 4; ++it) {
    const unsigned idx = (unsigned)(tid + it * 256) * 4u;
    *reinterpret_cast<f32x4*>(&Pj[idx]) =
        *reinterpret_cast<const f32x4*>(&proj[(unsigned)h * 4096 + idx]);
  }
  __syncthreads();
  const int mrow = w * 16 + (lane & 15);
  bf16x8 af[2];
#pragma unroll
  for (int kk = 0; kk < 2; ++kk)
#pragma unroll
    for (int e = 0; e < 8; ++e) {
      const int d = (lane >> 4) * 8 + kk * 32 + e;
      af[kk][e] = (short)f2bf(Pj[d * 64 + mrow]);
    }
  f32x4 accf[4] = {};
#pragma unroll
  for (int j = 0; j < 4; ++j)
#pragma unroll
    for (int kk = 0; kk < 2; ++kk)
      accf[j] = __builtin_amdgcn_mfma_f32_16x16x32_bf16(
          af[kk], frag64(Xs, j * 16 + (lane & 15), kk * 4 + (lane >> 4)), accf[j], 0, 0, 0);
#pragma unroll
  for (int j = 0; j < 4; ++j)
#pragma unroll
    for (int r = 0; r < 4; ++r) {
      float v = accf[j][r];
      accf[j][r] = (v > 0.f ? v : 0.f) * 0.125f;
    }
  // stage p' into Os swizzled as [t][m]
#pragma unroll
  for (int j = 0; j < 4; ++j) {
    const int t = j * 16 + (lane & 15);
#pragma unroll
    for (int r = 0; r < 4; ++r) {
      const int m = w * 16 + (lane >> 4) * 4 + r;
      Os[t * 64 + (((m >> 3) ^ (t & 7)) * 8) + (m & 7)] = f2bf(accf[j][r]);
    }
  }
  if (which) {
    float rs[4];
#pragma unroll
    for (int r = 0; r < 4; ++r) {
      float s = accf[0][r] + accf[1][r] + accf[2][r] + accf[3][r];
#pragma unroll
      for (int off = 1; off < 16; off <<= 1) s += __shfl_xor(s, off, 64);
      rs[r] = s;
    }
    if ((lane & 15) == 0) {
#pragma unroll
      for (int r = 0; r < 4; ++r) {
        const int m = w * 16 + (lane >> 4) * 4 + r;
        ksum[((unsigned)h * NCH + c) * 64u + m] = rs[r];
      }
    }
  }
  __syncthreads();
  // coalesced store of p' rows to qp/kp [h][t][m]
  unsigned short* dst = (which ? kp : qp) + ((unsigned)h * TT + c * 64) * 64;
  {
    const int t = tid >> 2;
#pragma unroll
    for (int q = 0; q < 2; ++q) {
      const int chunk = (tid & 3) * 2 + q;
      bf16x8 vle = *reinterpret_cast<const bf16x8*>(&Os[t * 64 + ((chunk ^ (t & 7)) * 8)]);
      *reinterpret_cast<bf16x8*>(&dst[t * 64 + chunk * 8]) = vle;
    }
  }
  if (which) {
    // fused chunk-KV: A-frags (rows m, k=t) from Os; B-frags (rows d, k=t) from VTs
    const int m = w * 16 + (lane & 15);
    bf16x8 afm[2];
#pragma unroll
    for (int kk = 0; kk < 2; ++kk)
#pragma unroll
      for (int e = 0; e < 8; ++e) {
        const int t = kk * 32 + (lane >> 4) * 8 + e;
        afm[kk][e] = (short)Os[t * 64 + (((m >> 3) ^ (t & 7)) << 3) + (m & 7)];
      }
    f32x4 acckv[4] = {};
#pragma unroll
    for (int j = 0; j < 4; ++j)
#pragma unroll
      for (int kk = 0; kk < 2; ++kk)
        acckv[j] = __builtin_amdgcn_mfma_f32_16x16x32_bf16(
            afm[kk], frag64(VTs, j * 16 + (lane & 15), kk * 4 + (lane >> 4)), acckv[j], 0, 0, 0);
    float* dkv = kvt + ((unsigned)h * NCH + c) * 4096u;
#pragma unroll
    for (int j = 0; j < 4; ++j) {
      const int d = j * 16 + (lane & 15);
      const int mq = w * 16 + (lane >> 4) * 4;
      *reinterpret_cast<f32x4*>(&dkv[(unsigned)d * 64 + mq]) = acckv[j];
    }
  }
}

// ---------------- Kernel 4: exclusive prefix over chunks (parallel) --------
__global__ __launch_bounds__(256) void k_prefix(const float* __restrict__ kvt,
                                                const float* __restrict__ ksum,
                                                unsigned short* __restrict__ st,
                                                float* __restrict__ z) {
  const int h = blockIdx.y;
  const unsigned e = blockIdx.x * 256u + threadIdx.x;
  float run = 0.f;
#pragma unroll
  for (int c = 0; c < NCH; ++c) {
    const unsigned idx = ((unsigned)h * NCH + c) * 4096u + e;
    st[idx] = f2bf(run);
    run += kvt[idx];
  }
  if (blockIdx.x == 0 && threadIdx.x < 64) {
    float zr = 0.f;
#pragma unroll
    for (int c = 0; c < NCH; ++c) {
      const unsigned idx = ((unsigned)h * NCH + c) * 64u + threadIdx.x;
      z[idx] = zr;
      zr += ksum[idx];
    }
  }
}

// ---------------- Kernel 5: per-(h,c) intra-chunk attention (MFMA) ---------
__global__ __launch_bounds__(256) void k_attn(const unsigned short* __restrict__ qp,
                                              const unsigned short* __restrict__ kp,
                                              const unsigned short* __restrict__ vt,
                                              const unsigned short* __restrict__ st,
                                              const float* __restrict__ z,
                                              unsigned short* __restrict__ attnb) {
  __shared__ unsigned short QPs[4096];
  __shared__ unsigned short KPs[4096];  // reused as A^bf16 after phase A
  __shared__ unsigned short VTs[4096];
  __shared__ unsigned short STs[4096];
  __shared__ float zsm[64];
  __shared__ float nsm[64];
  const int tid = threadIdx.x, lane = tid & 63, w = tid >> 6;
  const int c = blockIdx.x, h = blockIdx.y;
  stage_tile64(qp + ((unsigned)h * TT + c * 64) * 64, 64, QPs, w, lane);
  stage_tile64(kp + ((unsigned)h * TT + c * 64) * 64, 64, KPs, w, lane);
  stage_tile64(vt + (unsigned)h * 64 * TT + (unsigned)c * 64, TT, VTs, w, lane);
  stage_tile64(st + ((unsigned)h * NCH + c) * 4096u, 64, STs, w, lane);
  if (tid < 64) zsm[tid] = z[((unsigned)h * NCH + c) * 64u + tid];
  __syncthreads();
  const int tr = w * 16 + (lane & 15);
  bf16x8 afq[2];
#pragma unroll
  for (int kk = 0; kk < 2; ++kk) afq[kk] = frag64(QPs, tr, kk * 4 + (lane >> 4));
  f32x4 accA[4] = {};
#pragma unroll
  for (int j = 0; j < 4; ++j)
#pragma unroll
    for (int kk = 0; kk < 2; ++kk)
      accA[j] = __builtin_amdgcn_mfma_f32_16x16x32_bf16(
          afq[kk], frag64(KPs, j * 16 + (lane & 15), kk * 4 + (lane >> 4)), accA[j], 0, 0, 0);
  float rs[4] = {0.f, 0.f, 0.f, 0.f};
#pragma unroll
  for (int j = 0; j < 4; ++j) {
    const int s = j * 16 + (lane & 15);
#pragma unroll
    for (int r = 0; r < 4; ++r) {
      const int t = w * 16 + (lane >> 4) * 4 + r;
      float v = (s <= t) ? accA[j][r] : 0.f;
      accA[j][r] = v;
      rs[r] += v;
    }
  }
#pragma unroll
  for (int r = 0; r < 4; ++r)
#pragma unroll
    for (int off = 1; off < 16; off <<= 1) rs[r] += __shfl_xor(rs[r], off, 64);
  __syncthreads();
  if ((lane & 15) == 0) {
#pragma unroll
    for (int r = 0; r < 4; ++r) nsm[w * 16 + (lane >> 4) * 4 + r] = rs[r];
  }
#pragma unroll
  for (int j = 0; j < 4; ++j) {
    const int s = j * 16 + (lane & 15);
#pragma unroll
    for (int r = 0; r < 4; ++r) {
      const int t = w * 16 + (lane >> 4) * 4 + r;
      KPs[t * 64 + (((s >> 3) ^ (t & 7)) * 8) + (s & 7)] = f2bf(accA[j][r]);
    }
  }
  __syncthreads();
  {
    const int t = tid >> 2, part = tid & 3;
    float qz = 0.f;
#pragma unroll
    for (int mm = 0; mm < 16; ++mm) {
      const int m = part * 16 + mm;
      qz += bf2f(QPs[t * 64 + (((m >> 3) ^ (t & 7)) * 8) + (m & 7)]) * zsm[m];
    }
    qz += __shfl_xor(qz, 1, 64);
    qz += __shfl_xor(qz, 2, 64);
    if (part == 0) nsm[t] += qz + EPSV;
  }
  bf16x8 afa[2];
#pragma unroll
  for (int kk = 0; kk < 2; ++kk) afa[kk] = frag64(KPs, tr, kk * 4 + (lane >> 4));
  f32x4 acc[4] = {};
#pragma unroll
  for (int j = 0; j < 4; ++j) {
    const int br = j * 16 + (lane & 15);
#pragma unroll
    for (int kk = 0; kk < 2; ++kk) {
      acc[j] = __builtin_amdgcn_mfma_f32_16x16x32_bf16(
          afa[kk], frag64(VTs, br, kk * 4 + (lane >> 4)), acc[j], 0, 0, 0);
      acc[j] = __builtin_amdgcn_mfma_f32_16x16x32_bf16(
          afq[kk], frag64(STs, br, kk * 4 + (lane >> 4)), acc[j], 0, 0, 0);
    }
  }
  __syncthreads();
#pragma unroll
  for (int j = 0; j < 4; ++j) {
    const int d = j * 16 + (lane & 15);
#pragma unroll
    for (int r = 0; r < 4; ++r) {
      const int t = w * 16 + (lane >> 4) * 4 + r;
      attnb[(unsigned)(c * 64 + t) * CC + h * 64 + d] = f2bf(acc[j][r] / nsm[t]);
    }
  }
}

// ---------------- Kernel 6: out = attn @ w_out + b (128x64 tiles) ----------
__global__ __launch_bounds__(256) void k_out_mfma(const unsigned short* __restrict__ Abf,
                                                  const unsigned short* __restrict__ WoT,
                                                  const float* __restrict__ bias,
                                                  float* __restrict__ out) {
  __shared__ unsigned short As[8192];  // 128 x 64
  __shared__ unsigned short Bs[4096];  // 64 x 64
  const int tid = threadIdx.x, lane = tid & 63, w = tid >> 6;
  const int wm = w >> 1, wn = w & 1;
  // XCD-aware bijective swizzle (nwg = 256)
  int lin = blockIdx.y * 16 + blockIdx.x;
  int swz = (lin & 7) * 32 + (lin >> 3);
  const int bx = swz & 15, by = swz >> 4;
  const int m0 = by * 128, n0 = bx * 64;
  const int l8 = lane >> 3, l7 = lane & 7;
  const int kcg = (l7 ^ l8) * 8;
  f32x4 acc[4][2] = {};
  for (int k0 = 0; k0 < CC; k0 += 64) {
    if (k0) __syncthreads();
#pragma unroll
    for (int j = 0; j < 4; ++j) {
      const int inst = w * 4 + j;
      const int row = inst * 8 + l8;
      gload16(&Abf[(unsigned)(m0 + row) * CC + k0 + kcg], &As[inst * 512]);
    }
#pragma unroll
    for (int jj = 0; jj < 2; ++jj) {
      const int inst = w * 2 + jj;
      const int row = inst * 8 + l8;
      gload16(&WoT[(unsigned)(n0 + row) * CC + k0 + kcg], &Bs[inst * 512]);
    }
    __syncthreads();
#pragma unroll
    for (int kk = 0; kk < 2; ++kk) {
      bf16x8 af[4], bg[2];
#pragma unroll
      for (int i = 0; i < 4; ++i) {
        const int r = wm * 64 + i * 16 + (lane & 15);
        const int slot = (kk * 4 + (lane >> 4)) ^ (r & 7);
        af[i] = *reinterpret_cast<const bf16x8*>(&As[r * 64 + slot * 8]);
      }
#pragma unroll
      for (int j = 0; j < 2; ++j) {
        const int r = wn * 32 + j * 16 + (lane & 15);
        const int slot = (kk * 4 + (lane >> 4)) ^ (r & 7);
        bg[j] = *reinterpret_cast<const bf16x8*>(&Bs[r * 64 + slot * 8]);
      }
#pragma unroll
      for (int i = 0; i < 4; ++i)
#pragma unroll
        for (int j = 0; j < 2; ++j)
          acc[i][j] = __builtin_amdgcn_mfma_f32_16x16x32_bf16(af[i], bg[j],
                                                              acc[i][j], 0, 0, 0);
    }
  }
#pragma unroll
  for (int i = 0; i < 4; ++i) {
#pragma unroll
    for (int j = 0; j < 2; ++j) {
      const int n = n0 + wn * 32 + j * 16 + (lane & 15);
      const float bv = bias[n];
#pragma unroll
      for (int r = 0; r < 4; ++r) {
        const int m = m0 + wm * 64 + i * 16 + (lane >> 4) * 4 + r;
        out[(unsigned)m * CC + n] = acc[i][j][r] + bv;
      }
    }
  }
}

extern "C" void kernel_launch(void* const* d_in, const int* in_sizes, int n_in,
                              void* d_out, int out_size, void* d_ws, size_t ws_size,
                              hipStream_t stream) {
  const float* x = (const float*)d_in[0];
  const float* w_qkv = (const float*)d_in[1];
  const float* b_qkv = (const float*)d_in[2];
  const float* w_out = (const float*)d_in[3];
  const float* b_out = (const float*)d_in[4];
  const float* proj = (const float*)d_in[5];
  float* ws = (float*)d_ws;
  float* out = (float*)d_out;
  float* kvt = ws + OFF_KVT;
  float* ksum = ws + OFF_KS;
  float* zf = ws + OFF_Z;
  unsigned short* ub = (unsigned short*)(ws + OFF_U16);
  unsigned short* qbf = ub + U_QBF;
  unsigned short* kbf = ub + U_KBF;
  unsigned short* vt = ub + U_VT;
  unsigned short* qp = ub + U_QP;
  unsigned short* kp = ub + U_KP;
  unsigned short* st = ub + U_ST;
  unsigned short* xbf = ub + U_XBF;
  unsigned short* wqT = ub + U_WQT;
  unsigned short* woT = ub + U_WOT;
  unsigned short* attnb = xbf;  // alias: x_bf16 dead after k_qkv_mfma
  dim3 blk(256, 1, 1);
  k_prep<<<dim3(3072), blk, 0, stream>>>(x, w_qkv, w_out, xbf, wqT, woT);
  k_qkv_mfma<<<dim3(N_QKV / 128, TT / 128), blk, 0, stream>>>(xbf, wqT, b_qkv, qbf, kbf, vt);
  k_feat<<<dim3(NCH, HH, 2), blk, 0, stream>>>(proj, qbf, kbf, vt, qp, kp, kvt, ksum);
  k_prefix<<<dim3(16, HH), blk, 0, stream>>>(kvt, ksum, st, zf);
  k_attn<<<dim3(NCH, HH), blk, 0, stream>>>(qp, kp, vt, st, zf, attnb);
  k_out_mfma<<<dim3(CC / 64, TT / 128), blk, 0, stream>>>(attnb, woT, b_out, out);
}

// Round 7
// 71.929 us; speedup vs baseline: 1.3133x; 1.0900x over previous
//
#include <hip/hip_runtime.h>
#include <hip/hip_bf16.h>

#define TT 2048
#define CC 1024
#define HH 16
#define DD 64
#define FM 64
#define NCH 32
#define CL 64
#define N_QKV 3072
#define EPSV 1e-6f

// fp32 workspace region (float units)
#define OFF_KVT 0u          // KV^T fp32 [16][32][64d][64m]
#define OFF_KS  2097152u    // Ksum fp32 [16][32][64m]
#define OFF_Z   2129920u    // z fp32 [16][32][64m]
#define OFF_U16 2162688u    // bf16 region start (float units)
// bf16 region offsets (ushort units)
#define U_QBF 0u            // q bf16 [16][2048][64]
#define U_KBF 2097152u      // k bf16 [16][2048][64]
#define U_VT  4194304u      // v^T bf16 [16][64][2048]
#define U_QP  6291456u      // q' bf16 [16][2048][64m]
#define U_KP  8388608u      // k' bf16 [16][2048][64m]
#define U_ST  12582912u     // S^T bf16 [16][32][64d][64m]
#define U_XBF 14680064u     // x bf16 (later aliased as attnb)
#define U_WQT 16777216u     // w_qkv^T bf16 [3072][1024]
#define U_WOT 19922944u     // w_out^T bf16 [1024][1024]

typedef __attribute__((ext_vector_type(8))) short bf16x8;
typedef __attribute__((ext_vector_type(4))) float f32x4;
typedef __attribute__((ext_vector_type(4))) unsigned short u16x4;

__device__ __forceinline__ unsigned short f2bf(float f) {
  unsigned int u = __float_as_uint(f);
  u = (u + 0x7fffu + ((u >> 16) & 1u)) >> 16;
  return (unsigned short)u;
}
__device__ __forceinline__ float bf2f(unsigned short b) {
  return __uint_as_float(((unsigned)b) << 16);
}

__device__ __forceinline__ void gload16(const void* g, void* l) {
  __builtin_amdgcn_global_load_lds(
      (const __attribute__((address_space(1))) unsigned int*)g,
      (__attribute__((address_space(3))) unsigned int*)l, 16, 0, 0);
}

// stage a 64-row x 64-ushort (8KB) tile into LDS, XOR-swizzled (chunk^=row&7)
__device__ __forceinline__ void stage_tile64(const unsigned short* g, unsigned rowstride,
                                             unsigned short* lds, int w, int lane) {
  const int l8 = lane >> 3, l7 = lane & 7;
  const int kcg = (l7 ^ l8) * 8;
#pragma unroll
  for (int jj = 0; jj < 2; ++jj) {
    const int inst = w * 2 + jj;
    const int row = inst * 8 + l8;
    gload16(&g[(unsigned)row * rowstride + kcg], &lds[inst * 512]);
  }
}

// read an 8-element bf16 fragment from a swizzled 64x64 LDS tile
__device__ __forceinline__ bf16x8 frag64(const unsigned short* lds, int r, int kchunk) {
  const int slot = kchunk ^ (r & 7);
  return *reinterpret_cast<const bf16x8*>(&lds[r * 64 + slot * 8]);
}

// ---------------- Kernel 0: fused prep (xconv + 2 weight transposes) -------
__device__ __forceinline__ void transpose64_dev(const float* __restrict__ src,
                                                unsigned short* __restrict__ dst,
                                                int K, int N, int k0, int n0,
                                                float (*T)[68], int tid) {
#pragma unroll
  for (int it = 0; it < 4; ++it) {
    int f = tid + it * 256;
    int r = f >> 4, c4 = (f & 15) * 4;
    float4 v = *reinterpret_cast<const float4*>(&src[(unsigned)(k0 + r) * N + n0 + c4]);
    T[r][c4 + 0] = v.x; T[r][c4 + 1] = v.y;
    T[r][c4 + 2] = v.z; T[r][c4 + 3] = v.w;
  }
  __syncthreads();
#pragma unroll
  for (int it = 0; it < 4; ++it) {
    int f = tid + it * 256;
    int nl = f >> 4, kq = (f & 15) * 4;
    u16x4 o;
#pragma unroll
    for (int j = 0; j < 4; ++j) o[j] = f2bf(T[kq + j][nl]);
    *reinterpret_cast<u16x4*>(&dst[(unsigned)(n0 + nl) * K + k0 + kq]) = o;
  }
}

__global__ __launch_bounds__(256) void k_prep(const float* __restrict__ x,
                                              const float* __restrict__ wq,
                                              const float* __restrict__ wo,
                                              unsigned short* __restrict__ xbf,
                                              unsigned short* __restrict__ wqT,
                                              unsigned short* __restrict__ woT) {
  __shared__ float T[64][68];
  const int tid = threadIdx.x;
  int b = blockIdx.x;
  if (b < 2048) {  // x f32 -> bf16
    unsigned i = (unsigned)b * 1024u + (unsigned)tid * 4u;
    float4 v = *reinterpret_cast<const float4*>(&x[i]);
    u16x4 o;
    o[0] = f2bf(v.x); o[1] = f2bf(v.y); o[2] = f2bf(v.z); o[3] = f2bf(v.w);
    *reinterpret_cast<u16x4*>(&xbf[i]) = o;
    return;
  }
  b -= 2048;
  if (b < 768) {  // w_qkv [1024][3072] -> wqT [3072][1024]
    transpose64_dev(wq, wqT, CC, N_QKV, (b / 48) * 64, (b % 48) * 64, T, tid);
    return;
  }
  b -= 768;  // w_out [1024][1024] -> woT [1024][1024]
  transpose64_dev(wo, woT, CC, CC, (b / 16) * 64, (b % 16) * 64, T, tid);
}

// ---------------- Kernel 1: qkv GEMM (64x128 tiles, 3 blocks/CU) -----------
// scatter q/k bf16 [h][t][d], vT bf16 [h][d][t]
__global__ __launch_bounds__(256) void k_qkv_mfma(const unsigned short* __restrict__ Xbf,
                                                  const unsigned short* __restrict__ WqT,
                                                  const float* __restrict__ bias,
                                                  unsigned short* __restrict__ qbf,
                                                  unsigned short* __restrict__ kbf,
                                                  unsigned short* __restrict__ vt) {
  __shared__ unsigned short As[64 * 64];    // 8 KB
  __shared__ unsigned short Bs[128 * 64];   // 16 KB
  const int tid = threadIdx.x, lane = tid & 63, w = tid >> 6;
  const int wm = w >> 1, wn = w & 1;   // 2M x 2N warp layout (32 x 64 per warp)
  // XCD-aware bijective swizzle: nwg = 24*32 = 768, 768%8==0, cpx=96
  int lin = blockIdx.y * 24 + blockIdx.x;
  int swz = (lin & 7) * 96 + (lin >> 3);
  const int bx = swz % 24, by = swz / 24;
  const int m0b = by * 64, n0b = bx * 128;
  const int l8 = lane >> 3, l7 = lane & 7;
  const int kcg = (l7 ^ l8) * 8;
  f32x4 acc[2][4] = {};
  for (int k0 = 0; k0 < CC; k0 += 64) {
    if (k0) __syncthreads();
#pragma unroll
    for (int jj = 0; jj < 2; ++jj) {   // A: 64x64
      const int inst = w * 2 + jj;
      const int row = inst * 8 + l8;
      gload16(&Xbf[(unsigned)(m0b + row) * CC + k0 + kcg], &As[inst * 512]);
    }
#pragma unroll
    for (int jj = 0; jj < 4; ++jj) {   // B: 128x64
      const int inst = w * 4 + jj;
      const int row = inst * 8 + l8;
      gload16(&WqT[(unsigned)(n0b + row) * CC + k0 + kcg], &Bs[inst * 512]);
    }
    __syncthreads();
#pragma unroll
    for (int kk = 0; kk < 2; ++kk) {
      bf16x8 af[2], bg[4];
#pragma unroll
      for (int i = 0; i < 2; ++i) {
        const int r = wm * 32 + i * 16 + (lane & 15);
        const int slot = (kk * 4 + (lane >> 4)) ^ (r & 7);
        af[i] = *reinterpret_cast<const bf16x8*>(&As[r * 64 + slot * 8]);
      }
#pragma unroll
      for (int j = 0; j < 4; ++j) {
        const int r = wn * 64 + j * 16 + (lane & 15);
        const int slot = (kk * 4 + (lane >> 4)) ^ (r & 7);
        bg[j] = *reinterpret_cast<const bf16x8*>(&Bs[r * 64 + slot * 8]);
      }
#pragma unroll
      for (int i = 0; i < 2; ++i)
#pragma unroll
        for (int j = 0; j < 4; ++j)
          acc[i][j] = __builtin_amdgcn_mfma_f32_16x16x32_bf16(af[i], bg[j],
                                                              acc[i][j], 0, 0, 0);
    }
  }
  const int m0 = m0b + wm * 32;
  const int n0w = n0b + wn * 64;       // one (sel,h) per warp
  const int sel = n0w >> 10;
  const int h = (n0w & 1023) >> 6;
#pragma unroll
  for (int i = 0; i < 2; ++i) {
    const int t0 = m0 + i * 16 + (lane >> 4) * 4;
#pragma unroll
    for (int j = 0; j < 4; ++j) {
      const int n = n0w + j * 16 + (lane & 15);
      const float bv = bias[n];
      const int d = n & 63;
      if (sel == 2) {
        u16x4 o;
#pragma unroll
        for (int r = 0; r < 4; ++r) o[r] = f2bf(acc[i][j][r] + bv);
        *reinterpret_cast<u16x4*>(&vt[((unsigned)h * 64 + d) * TT + t0]) = o;
      } else {
        unsigned short* dst = (sel ? kbf : qbf) + (unsigned)h * TT * 64 + d;
#pragma unroll
        for (int r = 0; r < 4; ++r)
          dst[(unsigned)(t0 + r) * 64] = f2bf(acc[i][j][r] + bv);
      }
    }
  }
}

// ---------------- Kernel 2: MFMA feature map + fused per-chunk KV ----------
__global__ __launch_bounds__(256) void k_feat(const float* __restrict__ proj,
                                              const unsigned short* __restrict__ qbf,
                                              const unsigned short* __restrict__ kbf,
                                              const unsigned short* __restrict__ vt,
                                              unsigned short* __restrict__ qp,
                                              unsigned short* __restrict__ kp,
                                              float* __restrict__ kvt,
                                              float* __restrict__ ksum) {
  __shared__ unsigned short Xs[4096];
  __shared__ float Pj[4096];
  __shared__ unsigned short Os[4096];
  __shared__ unsigned short VTs[4096];
  const int tid = threadIdx.x, lane = tid & 63, w = tid >> 6;
  const int c = blockIdx.x, h = blockIdx.y, which = blockIdx.z;
  const unsigned short* src = (which ? kbf : qbf) + ((unsigned)h * TT + c * 64) * 64;
  stage_tile64(src, 64, Xs, w, lane);
  if (which) stage_tile64(vt + (unsigned)h * 64 * TT + (unsigned)c * 64, TT, VTs, w, lane);
#pragma unroll
  for (int it = 0; it < 4; ++it) {
    const unsigned idx = (unsigned)(tid + it * 256) * 4u;
    *reinterpret_cast<f32x4*>(&Pj[idx]) =
        *reinterpret_cast<const f32x4*>(&proj[(unsigned)h * 4096 + idx]);
  }
  __syncthreads();
  const int mrow = w * 16 + (lane & 15);
  bf16x8 af[2];
#pragma unroll
  for (int kk = 0; kk < 2; ++kk)
#pragma unroll
    for (int e = 0; e < 8; ++e) {
      const int d = (lane >> 4) * 8 + kk * 32 + e;
      af[kk][e] = (short)f2bf(Pj[d * 64 + mrow]);
    }
  f32x4 accf[4] = {};
#pragma unroll
  for (int j = 0; j < 4; ++j)
#pragma unroll
    for (int kk = 0; kk < 2; ++kk)
      accf[j] = __builtin_amdgcn_mfma_f32_16x16x32_bf16(
          af[kk], frag64(Xs, j * 16 + (lane & 15), kk * 4 + (lane >> 4)), accf[j], 0, 0, 0);
#pragma unroll
  for (int j = 0; j < 4; ++j)
#pragma unroll
    for (int r = 0; r < 4; ++r) {
      float v = accf[j][r];
      accf[j][r] = (v > 0.f ? v : 0.f) * 0.125f;
    }
  // stage p' into Os swizzled as [t][m]
#pragma unroll
  for (int j = 0; j < 4; ++j) {
    const int t = j * 16 + (lane & 15);
#pragma unroll
    for (int r = 0; r < 4; ++r) {
      const int m = w * 16 + (lane >> 4) * 4 + r;
      Os[t * 64 + (((m >> 3) ^ (t & 7)) * 8) + (m & 7)] = f2bf(accf[j][r]);
    }
  }
  if (which) {
    float rs[4];
#pragma unroll
    for (int r = 0; r < 4; ++r) {
      float s = accf[0][r] + accf[1][r] + accf[2][r] + accf[3][r];
#pragma unroll
      for (int off = 1; off < 16; off <<= 1) s += __shfl_xor(s, off, 64);
      rs[r] = s;
    }
    if ((lane & 15) == 0) {
#pragma unroll
      for (int r = 0; r < 4; ++r) {
        const int m = w * 16 + (lane >> 4) * 4 + r;
        ksum[((unsigned)h * NCH + c) * 64u + m] = rs[r];
      }
    }
  }
  __syncthreads();
  // coalesced store of p' rows to qp/kp [h][t][m]
  unsigned short* dst = (which ? kp : qp) + ((unsigned)h * TT + c * 64) * 64;
  {
    const int t = tid >> 2;
#pragma unroll
    for (int q = 0; q < 2; ++q) {
      const int chunk = (tid & 3) * 2 + q;
      bf16x8 vle = *reinterpret_cast<const bf16x8*>(&Os[t * 64 + ((chunk ^ (t & 7)) * 8)]);
      *reinterpret_cast<bf16x8*>(&dst[t * 64 + chunk * 8]) = vle;
    }
  }
  if (which) {
    // fused chunk-KV: A-frags (rows m, k=t) from Os; B-frags (rows d, k=t) from VTs
    const int m = w * 16 + (lane & 15);
    bf16x8 afm[2];
#pragma unroll
    for (int kk = 0; kk < 2; ++kk)
#pragma unroll
      for (int e = 0; e < 8; ++e) {
        const int t = kk * 32 + (lane >> 4) * 8 + e;
        afm[kk][e] = (short)Os[t * 64 + (((m >> 3) ^ (t & 7)) << 3) + (m & 7)];
      }
    f32x4 acckv[4] = {};
#pragma unroll
    for (int j = 0; j < 4; ++j)
#pragma unroll
      for (int kk = 0; kk < 2; ++kk)
        acckv[j] = __builtin_amdgcn_mfma_f32_16x16x32_bf16(
            afm[kk], frag64(VTs, j * 16 + (lane & 15), kk * 4 + (lane >> 4)), acckv[j], 0, 0, 0);
    float* dkv = kvt + ((unsigned)h * NCH + c) * 4096u;
#pragma unroll
    for (int j = 0; j < 4; ++j) {
      const int d = j * 16 + (lane & 15);
      const int mq = w * 16 + (lane >> 4) * 4;
      *reinterpret_cast<f32x4*>(&dkv[(unsigned)d * 64 + mq]) = acckv[j];
    }
  }
}

// ---------------- Kernel 4: exclusive prefix over chunks (parallel) --------
__global__ __launch_bounds__(256) void k_prefix(const float* __restrict__ kvt,
                                                const float* __restrict__ ksum,
                                                unsigned short* __restrict__ st,
                                                float* __restrict__ z) {
  const int h = blockIdx.y;
  const unsigned e = blockIdx.x * 256u + threadIdx.x;
  float run = 0.f;
#pragma unroll
  for (int c = 0; c < NCH; ++c) {
    const unsigned idx = ((unsigned)h * NCH + c) * 4096u + e;
    st[idx] = f2bf(run);
    run += kvt[idx];
  }
  if (blockIdx.x == 0 && threadIdx.x < 64) {
    float zr = 0.f;
#pragma unroll
    for (int c = 0; c < NCH; ++c) {
      const unsigned idx = ((unsigned)h * NCH + c) * 64u + threadIdx.x;
      z[idx] = zr;
      zr += ksum[idx];
    }
  }
}

// ---------------- Kernel 5: per-(h,c) intra-chunk attention (MFMA) ---------
__global__ __launch_bounds__(256) void k_attn(const unsigned short* __restrict__ qp,
                                              const unsigned short* __restrict__ kp,
                                              const unsigned short* __restrict__ vt,
                                              const unsigned short* __restrict__ st,
                                              const float* __restrict__ z,
                                              unsigned short* __restrict__ attnb) {
  __shared__ unsigned short QPs[4096];
  __shared__ unsigned short KPs[4096];  // reused as A^bf16 after phase A
  __shared__ unsigned short VTs[4096];
  __shared__ unsigned short STs[4096];
  __shared__ float zsm[64];
  __shared__ float nsm[64];
  const int tid = threadIdx.x, lane = tid & 63, w = tid >> 6;
  const int c = blockIdx.x, h = blockIdx.y;
  stage_tile64(qp + ((unsigned)h * TT + c * 64) * 64, 64, QPs, w, lane);
  stage_tile64(kp + ((unsigned)h * TT + c * 64) * 64, 64, KPs, w, lane);
  stage_tile64(vt + (unsigned)h * 64 * TT + (unsigned)c * 64, TT, VTs, w, lane);
  stage_tile64(st + ((unsigned)h * NCH + c) * 4096u, 64, STs, w, lane);
  if (tid < 64) zsm[tid] = z[((unsigned)h * NCH + c) * 64u + tid];
  __syncthreads();
  const int tr = w * 16 + (lane & 15);
  bf16x8 afq[2];
#pragma unroll
  for (int kk = 0; kk < 2; ++kk) afq[kk] = frag64(QPs, tr, kk * 4 + (lane >> 4));
  f32x4 accA[4] = {};
#pragma unroll
  for (int j = 0; j < 4; ++j)
#pragma unroll
    for (int kk = 0; kk < 2; ++kk)
      accA[j] = __builtin_amdgcn_mfma_f32_16x16x32_bf16(
          afq[kk], frag64(KPs, j * 16 + (lane & 15), kk * 4 + (lane >> 4)), accA[j], 0, 0, 0);
  float rs[4] = {0.f, 0.f, 0.f, 0.f};
#pragma unroll
  for (int j = 0; j < 4; ++j) {
    const int s = j * 16 + (lane & 15);
#pragma unroll
    for (int r = 0; r < 4; ++r) {
      const int t = w * 16 + (lane >> 4) * 4 + r;
      float v = (s <= t) ? accA[j][r] : 0.f;
      accA[j][r] = v;
      rs[r] += v;
    }
  }
#pragma unroll
  for (int r = 0; r < 4; ++r)
#pragma unroll
    for (int off = 1; off < 16; off <<= 1) rs[r] += __shfl_xor(rs[r], off, 64);
  __syncthreads();
  if ((lane & 15) == 0) {
#pragma unroll
    for (int r = 0; r < 4; ++r) nsm[w * 16 + (lane >> 4) * 4 + r] = rs[r];
  }
#pragma unroll
  for (int j = 0; j < 4; ++j) {
    const int s = j * 16 + (lane & 15);
#pragma unroll
    for (int r = 0; r < 4; ++r) {
      const int t = w * 16 + (lane >> 4) * 4 + r;
      KPs[t * 64 + (((s >> 3) ^ (t & 7)) * 8) + (s & 7)] = f2bf(accA[j][r]);
    }
  }
  __syncthreads();
  {
    const int t = tid >> 2, part = tid & 3;
    float qz = 0.f;
#pragma unroll
    for (int mm = 0; mm < 16; ++mm) {
      const int m = part * 16 + mm;
      qz += bf2f(QPs[t * 64 + (((m >> 3) ^ (t & 7)) * 8) + (m & 7)]) * zsm[m];
    }
    qz += __shfl_xor(qz, 1, 64);
    qz += __shfl_xor(qz, 2, 64);
    if (part == 0) nsm[t] += qz + EPSV;
  }
  bf16x8 afa[2];
#pragma unroll
  for (int kk = 0; kk < 2; ++kk) afa[kk] = frag64(KPs, tr, kk * 4 + (lane >> 4));
  f32x4 acc[4] = {};
#pragma unroll
  for (int j = 0; j < 4; ++j) {
    const int br = j * 16 + (lane & 15);
#pragma unroll
    for (int kk = 0; kk < 2; ++kk) {
      acc[j] = __builtin_amdgcn_mfma_f32_16x16x32_bf16(
          afa[kk], frag64(VTs, br, kk * 4 + (lane >> 4)), acc[j], 0, 0, 0);
      acc[j] = __builtin_amdgcn_mfma_f32_16x16x32_bf16(
          afq[kk], frag64(STs, br, kk * 4 + (lane >> 4)), acc[j], 0, 0, 0);
    }
  }
  __syncthreads();
#pragma unroll
  for (int j = 0; j < 4; ++j) {
    const int d = j * 16 + (lane & 15);
#pragma unroll
    for (int r = 0; r < 4; ++r) {
      const int t = w * 16 + (lane >> 4) * 4 + r;
      attnb[(unsigned)(c * 64 + t) * CC + h * 64 + d] = f2bf(acc[j][r] / nsm[t]);
    }
  }
}

// ---------------- Kernel 6: out = attn @ w_out + b (64x64 tiles, 2/CU) -----
__global__ __launch_bounds__(256) void k_out_mfma(const unsigned short* __restrict__ Abf,
                                                  const unsigned short* __restrict__ WoT,
                                                  const float* __restrict__ bias,
                                                  float* __restrict__ out) {
  __shared__ unsigned short As[4096];  // 64 x 64
  __shared__ unsigned short Bs[4096];  // 64 x 64
  const int tid = threadIdx.x, lane = tid & 63, w = tid >> 6;
  const int wm = w >> 1, wn = w & 1;   // 2M x 2N, 32x32 per warp
  // XCD-aware bijective swizzle (nwg = 16*32 = 512, cpx=64)
  int lin = blockIdx.y * 16 + blockIdx.x;
  int swz = (lin & 7) * 64 + (lin >> 3);
  const int bx = swz & 15, by = swz >> 4;
  const int m0 = by * 64, n0 = bx * 64;
  const int l8 = lane >> 3, l7 = lane & 7;
  const int kcg = (l7 ^ l8) * 8;
  f32x4 acc[2][2] = {};
  for (int k0 = 0; k0 < CC; k0 += 64) {
    if (k0) __syncthreads();
#pragma unroll
    for (int jj = 0; jj < 2; ++jj) {
      const int inst = w * 2 + jj;
      const int row = inst * 8 + l8;
      gload16(&Abf[(unsigned)(m0 + row) * CC + k0 + kcg], &As[inst * 512]);
      gload16(&WoT[(unsigned)(n0 + row) * CC + k0 + kcg], &Bs[inst * 512]);
    }
    __syncthreads();
#pragma unroll
    for (int kk = 0; kk < 2; ++kk) {
      bf16x8 af[2], bg[2];
#pragma unroll
      for (int i = 0; i < 2; ++i) {
        const int r = wm * 32 + i * 16 + (lane & 15);
        const int slot = (kk * 4 + (lane >> 4)) ^ (r & 7);
        af[i] = *reinterpret_cast<const bf16x8*>(&As[r * 64 + slot * 8]);
      }
#pragma unroll
      for (int j = 0; j < 2; ++j) {
        const int r = wn * 32 + j * 16 + (lane & 15);
        const int slot = (kk * 4 + (lane >> 4)) ^ (r & 7);
        bg[j] = *reinterpret_cast<const bf16x8*>(&Bs[r * 64 + slot * 8]);
      }
#pragma unroll
      for (int i = 0; i < 2; ++i)
#pragma unroll
        for (int j = 0; j < 2; ++j)
          acc[i][j] = __builtin_amdgcn_mfma_f32_16x16x32_bf16(af[i], bg[j],
                                                              acc[i][j], 0, 0, 0);
    }
  }
#pragma unroll
  for (int i = 0; i < 2; ++i) {
#pragma unroll
    for (int j = 0; j < 2; ++j) {
      const int n = n0 + wn * 32 + j * 16 + (lane & 15);
      const float bv = bias[n];
#pragma unroll
      for (int r = 0; r < 4; ++r) {
        const int m = m0 + wm * 32 + i * 16 + (lane >> 4) * 4 + r;
        out[(unsigned)m * CC + n] = acc[i][j][r] + bv;
      }
    }
  }
}

extern "C" void kernel_launch(void* const* d_in, const int* in_sizes, int n_in,
                              void* d_out, int out_size, void* d_ws, size_t ws_size,
                              hipStream_t stream) {
  const float* x = (const float*)d_in[0];
  const float* w_qkv = (const float*)d_in[1];
  const float* b_qkv = (const float*)d_in[2];
  const float* w_out = (const float*)d_in[3];
  const float* b_out = (const float*)d_in[4];
  const float* proj = (const float*)d_in[5];
  float* ws = (float*)d_ws;
  float* out = (float*)d_out;
  float* kvt = ws + OFF_KVT;
  float* ksum = ws + OFF_KS;
  float* zf = ws + OFF_Z;
  unsigned short* ub = (unsigned short*)(ws + OFF_U16);
  unsigned short* qbf = ub + U_QBF;
  unsigned short* kbf = ub + U_KBF;
  unsigned short* vt = ub + U_VT;
  unsigned short* qp = ub + U_QP;
  unsigned short* kp = ub + U_KP;
  unsigned short* st = ub + U_ST;
  unsigned short* xbf = ub + U_XBF;
  unsigned short* wqT = ub + U_WQT;
  unsigned short* woT = ub + U_WOT;
  unsigned short* attnb = xbf;  // alias: x_bf16 dead after k_qkv_mfma
  dim3 blk(256, 1, 1);
  k_prep<<<dim3(3072), blk, 0, stream>>>(x, w_qkv, w_out, xbf, wqT, woT);
  k_qkv_mfma<<<dim3(N_QKV / 128, TT / 64), blk, 0, stream>>>(xbf, wqT, b_qkv, qbf, kbf, vt);
  k_feat<<<dim3(NCH, HH, 2), blk, 0, stream>>>(proj, qbf, kbf, vt, qp, kp, kvt, ksum);
  k_prefix<<<dim3(16, HH), blk, 0, stream>>>(kvt, ksum, st, zf);
  k_attn<<<dim3(NCH, HH), blk, 0, stream>>>(qp, kp, vt, st, zf, attnb);
  k_out_mfma<<<dim3(CC / 64, TT / 64), blk, 0, stream>>>(attnb, woT, b_out, out);
}

// Round 8
// 70.527 us; speedup vs baseline: 1.3394x; 1.0199x over previous
//
#include <hip/hip_runtime.h>
#include <hip/hip_bf16.h>

#define TT 2048
#define CC 1024
#define HH 16
#define DD 64
#define FM 64
#define NCH 32
#define CL 64
#define N_QKV 3072
#define EPSV 1e-6f

// fp32 workspace region (float units)
#define OFF_KS  0u          // Ksum fp32 [16][32][64m]
#define OFF_Z   32768u      // z fp32 [16][32][64m]
#define OFF_U16 65536u      // bf16 region start (float units)
// bf16 region offsets (ushort units)
#define U_KVT 0u            // KV^T bf16 [16][32][64d][64m]
#define U_QBF 2097152u      // q bf16 [16][2048][64]
#define U_KBF 4194304u      // k bf16 [16][2048][64]
#define U_VT  6291456u      // v^T bf16 [16][64][2048]
#define U_QP  8388608u      // q' bf16 [16][2048][64m]
#define U_KP  10485760u     // k' bf16 [16][2048][64m]
#define U_ST  12582912u     // S^T bf16 [16][32][64d][64m]
#define U_XBF 14680064u     // x bf16 (later aliased as attnb)
#define U_WQT 16777216u     // w_qkv^T bf16 [3072][1024]
#define U_WOT 19922944u     // w_out^T bf16 [1024][1024]

typedef __attribute__((ext_vector_type(8))) short bf16x8;
typedef __attribute__((ext_vector_type(4))) float f32x4;
typedef __attribute__((ext_vector_type(4))) unsigned short u16x4;

__device__ __forceinline__ unsigned short f2bf(float f) {
  unsigned int u = __float_as_uint(f);
  u = (u + 0x7fffu + ((u >> 16) & 1u)) >> 16;
  return (unsigned short)u;
}
__device__ __forceinline__ float bf2f(unsigned short b) {
  return __uint_as_float(((unsigned)b) << 16);
}

__device__ __forceinline__ void gload16(const void* g, void* l) {
  __builtin_amdgcn_global_load_lds(
      (const __attribute__((address_space(1))) unsigned int*)g,
      (__attribute__((address_space(3))) unsigned int*)l, 16, 0, 0);
}

// stage a 64-row x 64-ushort (8KB) tile into LDS, XOR-swizzled (chunk^=row&7)
__device__ __forceinline__ void stage_tile64(const unsigned short* g, unsigned rowstride,
                                             unsigned short* lds, int w, int lane) {
  const int l8 = lane >> 3, l7 = lane & 7;
  const int kcg = (l7 ^ l8) * 8;
#pragma unroll
  for (int jj = 0; jj < 2; ++jj) {
    const int inst = w * 2 + jj;
    const int row = inst * 8 + l8;
    gload16(&g[(unsigned)row * rowstride + kcg], &lds[inst * 512]);
  }
}

// read an 8-element bf16 fragment from a swizzled 64x64 LDS tile
__device__ __forceinline__ bf16x8 frag64(const unsigned short* lds, int r, int kchunk) {
  const int slot = kchunk ^ (r & 7);
  return *reinterpret_cast<const bf16x8*>(&lds[r * 64 + slot * 8]);
}

// ---------------- Kernel 0: fused prep (xconv + 2 weight transposes) -------
__device__ __forceinline__ void transpose64_dev(const float* __restrict__ src,
                                                unsigned short* __restrict__ dst,
                                                int K, int N, int k0, int n0,
                                                float (*T)[68], int tid) {
#pragma unroll
  for (int it = 0; it < 4; ++it) {
    int f = tid + it * 256;
    int r = f >> 4, c4 = (f & 15) * 4;
    float4 v = *reinterpret_cast<const float4*>(&src[(unsigned)(k0 + r) * N + n0 + c4]);
    T[r][c4 + 0] = v.x; T[r][c4 + 1] = v.y;
    T[r][c4 + 2] = v.z; T[r][c4 + 3] = v.w;
  }
  __syncthreads();
#pragma unroll
  for (int it = 0; it < 4; ++it) {
    int f = tid + it * 256;
    int nl = f >> 4, kq = (f & 15) * 4;
    u16x4 o;
#pragma unroll
    for (int j = 0; j < 4; ++j) o[j] = f2bf(T[kq + j][nl]);
    *reinterpret_cast<u16x4*>(&dst[(unsigned)(n0 + nl) * K + k0 + kq]) = o;
  }
}

__global__ __launch_bounds__(256) void k_prep(const float* __restrict__ x,
                                              const float* __restrict__ wq,
                                              const float* __restrict__ wo,
                                              unsigned short* __restrict__ xbf,
                                              unsigned short* __restrict__ wqT,
                                              unsigned short* __restrict__ woT) {
  __shared__ float T[64][68];
  const int tid = threadIdx.x;
  int b = blockIdx.x;
  if (b < 2048) {  // x f32 -> bf16
    unsigned i = (unsigned)b * 1024u + (unsigned)tid * 4u;
    float4 v = *reinterpret_cast<const float4*>(&x[i]);
    u16x4 o;
    o[0] = f2bf(v.x); o[1] = f2bf(v.y); o[2] = f2bf(v.z); o[3] = f2bf(v.w);
    *reinterpret_cast<u16x4*>(&xbf[i]) = o;
    return;
  }
  b -= 2048;
  if (b < 768) {  // w_qkv [1024][3072] -> wqT [3072][1024]
    transpose64_dev(wq, wqT, CC, N_QKV, (b / 48) * 64, (b % 48) * 64, T, tid);
    return;
  }
  b -= 768;  // w_out [1024][1024] -> woT [1024][1024]
  transpose64_dev(wo, woT, CC, CC, (b / 16) * 64, (b % 16) * 64, T, tid);
}

// ---------------- Kernel 1: qkv GEMM (64x128 tiles, 3 blocks/CU) -----------
// LDS-coalesced epilogue: q/k bf16 [h][t][d], vT bf16 [h][d][t]
__global__ __launch_bounds__(256) void k_qkv_mfma(const unsigned short* __restrict__ Xbf,
                                                  const unsigned short* __restrict__ WqT,
                                                  const float* __restrict__ bias,
                                                  unsigned short* __restrict__ qbf,
                                                  unsigned short* __restrict__ kbf,
                                                  unsigned short* __restrict__ vt) {
  __shared__ unsigned short LDSU[12288];  // As 64x64 | Bs 128x64 ; epilogue: 4x 32x64
  unsigned short* As = LDSU;
  unsigned short* Bs = LDSU + 4096;
  const int tid = threadIdx.x, lane = tid & 63, w = tid >> 6;
  const int wm = w >> 1, wn = w & 1;   // 2M x 2N warp layout (32 x 64 per warp)
  // XCD-aware bijective swizzle: nwg = 24*32 = 768, 768%8==0, cpx=96
  int lin = blockIdx.y * 24 + blockIdx.x;
  int swz = (lin & 7) * 96 + (lin >> 3);
  const int bx = swz % 24, by = swz / 24;
  const int m0b = by * 64, n0b = bx * 128;
  const int l8 = lane >> 3, l7 = lane & 7;
  const int kcg = (l7 ^ l8) * 8;
  f32x4 acc[2][4] = {};
  for (int k0 = 0; k0 < CC; k0 += 64) {
    if (k0) __syncthreads();
#pragma unroll
    for (int jj = 0; jj < 2; ++jj) {   // A: 64x64
      const int inst = w * 2 + jj;
      const int row = inst * 8 + l8;
      gload16(&Xbf[(unsigned)(m0b + row) * CC + k0 + kcg], &As[inst * 512]);
    }
#pragma unroll
    for (int jj = 0; jj < 4; ++jj) {   // B: 128x64
      const int inst = w * 4 + jj;
      const int row = inst * 8 + l8;
      gload16(&WqT[(unsigned)(n0b + row) * CC + k0 + kcg], &Bs[inst * 512]);
    }
    __syncthreads();
#pragma unroll
    for (int kk = 0; kk < 2; ++kk) {
      bf16x8 af[2], bg[4];
#pragma unroll
      for (int i = 0; i < 2; ++i) {
        const int r = wm * 32 + i * 16 + (lane & 15);
        const int slot = (kk * 4 + (lane >> 4)) ^ (r & 7);
        af[i] = *reinterpret_cast<const bf16x8*>(&As[r * 64 + slot * 8]);
      }
#pragma unroll
      for (int j = 0; j < 4; ++j) {
        const int r = wn * 64 + j * 16 + (lane & 15);
        const int slot = (kk * 4 + (lane >> 4)) ^ (r & 7);
        bg[j] = *reinterpret_cast<const bf16x8*>(&Bs[r * 64 + slot * 8]);
      }
#pragma unroll
      for (int i = 0; i < 2; ++i)
#pragma unroll
        for (int j = 0; j < 4; ++j)
          acc[i][j] = __builtin_amdgcn_mfma_f32_16x16x32_bf16(af[i], bg[j],
                                                              acc[i][j], 0, 0, 0);
    }
  }
  const int n0w = n0b + wn * 64;       // one (sel,h) per warp (block-uniform sel)
  const int sel = n0w >> 10;
  const int h = (n0w & 1023) >> 6;
  const int t0w = m0b + wm * 32;
  float bvj[4];
#pragma unroll
  for (int j = 0; j < 4; ++j) bvj[j] = bias[n0w + j * 16 + (lane & 15)];
  __syncthreads();  // all MFMA reads of LDS done
  // stage warp's 32t x 64d tile (+bias, bf16) into private quadrant, swizzled
  unsigned short* myT = LDSU + w * 2048;
#pragma unroll
  for (int i = 0; i < 2; ++i)
#pragma unroll
    for (int j = 0; j < 4; ++j) {
      const int d = j * 16 + (lane & 15);
#pragma unroll
      for (int r = 0; r < 4; ++r) {
        const int t = i * 16 + (lane >> 4) * 4 + r;
        myT[t * 64 + (((d >> 3) ^ (t & 7)) << 3) + (d & 7)] = f2bf(acc[i][j][r] + bvj[j]);
      }
    }
  if (sel == 2) {
    // vT [h][d][t]: per lane 4x bf16x8 along t (64B-line writes)
#pragma unroll
    for (int q = 0; q < 4; ++q) {
      const int cid = q * 64 + lane;
      const int d = cid >> 2, tc = cid & 3;
      bf16x8 o;
#pragma unroll
      for (int e = 0; e < 8; ++e) {
        const int t = tc * 8 + e;
        o[e] = (short)myT[t * 64 + (((d >> 3) ^ (t & 7)) << 3) + (d & 7)];
      }
      *reinterpret_cast<bf16x8*>(&vt[((unsigned)h * 64 + d) * TT + t0w + tc * 8]) = o;
    }
  } else {
    // q/k [h][t][d]: fully contiguous 1KB per store instruction
    unsigned short* dst0 = (sel ? kbf : qbf) + ((unsigned)h * TT + (unsigned)t0w) * 64u;
#pragma unroll
    for (int q = 0; q < 4; ++q) {
      const int cid = q * 64 + lane;
      const int t = cid >> 3, dc = cid & 7;
      bf16x8 o = *reinterpret_cast<const bf16x8*>(&myT[t * 64 + ((dc ^ (t & 7)) << 3)]);
      *reinterpret_cast<bf16x8*>(&dst0[(unsigned)cid * 8]) = o;
    }
  }
}

// ---------------- Kernel 2: MFMA feature map + fused per-chunk KV ----------
__global__ __launch_bounds__(256) void k_feat(const float* __restrict__ proj,
                                              const unsigned short* __restrict__ qbf,
                                              const unsigned short* __restrict__ kbf,
                                              const unsigned short* __restrict__ vt,
                                              unsigned short* __restrict__ qp,
                                              unsigned short* __restrict__ kp,
                                              unsigned short* __restrict__ kvt,
                                              float* __restrict__ ksum) {
  __shared__ unsigned short Xs[4096];
  __shared__ float Pj[4096];
  __shared__ unsigned short Os[4096];
  __shared__ unsigned short VTs[4096];
  const int tid = threadIdx.x, lane = tid & 63, w = tid >> 6;
  const int c = blockIdx.x, h = blockIdx.y, which = blockIdx.z;
  const unsigned short* src = (which ? kbf : qbf) + ((unsigned)h * TT + c * 64) * 64;
  stage_tile64(src, 64, Xs, w, lane);
  if (which) stage_tile64(vt + (unsigned)h * 64 * TT + (unsigned)c * 64, TT, VTs, w, lane);
#pragma unroll
  for (int it = 0; it < 4; ++it) {
    const unsigned idx = (unsigned)(tid + it * 256) * 4u;
    *reinterpret_cast<f32x4*>(&Pj[idx]) =
        *reinterpret_cast<const f32x4*>(&proj[(unsigned)h * 4096 + idx]);
  }
  __syncthreads();
  const int mrow = w * 16 + (lane & 15);
  bf16x8 af[2];
#pragma unroll
  for (int kk = 0; kk < 2; ++kk)
#pragma unroll
    for (int e = 0; e < 8; ++e) {
      const int d = (lane >> 4) * 8 + kk * 32 + e;
      af[kk][e] = (short)f2bf(Pj[d * 64 + mrow]);
    }
  f32x4 accf[4] = {};
#pragma unroll
  for (int j = 0; j < 4; ++j)
#pragma unroll
    for (int kk = 0; kk < 2; ++kk)
      accf[j] = __builtin_amdgcn_mfma_f32_16x16x32_bf16(
          af[kk], frag64(Xs, j * 16 + (lane & 15), kk * 4 + (lane >> 4)), accf[j], 0, 0, 0);
#pragma unroll
  for (int j = 0; j < 4; ++j)
#pragma unroll
    for (int r = 0; r < 4; ++r) {
      float v = accf[j][r];
      accf[j][r] = (v > 0.f ? v : 0.f) * 0.125f;
    }
  // stage p' into Os swizzled as [t][m]
#pragma unroll
  for (int j = 0; j < 4; ++j) {
    const int t = j * 16 + (lane & 15);
#pragma unroll
    for (int r = 0; r < 4; ++r) {
      const int m = w * 16 + (lane >> 4) * 4 + r;
      Os[t * 64 + (((m >> 3) ^ (t & 7)) * 8) + (m & 7)] = f2bf(accf[j][r]);
    }
  }
  if (which) {
    float rs[4];
#pragma unroll
    for (int r = 0; r < 4; ++r) {
      float s = accf[0][r] + accf[1][r] + accf[2][r] + accf[3][r];
#pragma unroll
      for (int off = 1; off < 16; off <<= 1) s += __shfl_xor(s, off, 64);
      rs[r] = s;
    }
    if ((lane & 15) == 0) {
#pragma unroll
      for (int r = 0; r < 4; ++r) {
        const int m = w * 16 + (lane >> 4) * 4 + r;
        ksum[((unsigned)h * NCH + c) * 64u + m] = rs[r];
      }
    }
  }
  __syncthreads();
  // coalesced store of p' rows to qp/kp [h][t][m]
  unsigned short* dst = (which ? kp : qp) + ((unsigned)h * TT + c * 64) * 64;
  {
    const int t = tid >> 2;
#pragma unroll
    for (int q = 0; q < 2; ++q) {
      const int chunk = (tid & 3) * 2 + q;
      bf16x8 vle = *reinterpret_cast<const bf16x8*>(&Os[t * 64 + ((chunk ^ (t & 7)) * 8)]);
      *reinterpret_cast<bf16x8*>(&dst[t * 64 + chunk * 8]) = vle;
    }
  }
  if (which) {
    // fused chunk-KV: A-frags (rows m, k=t) from Os; B-frags (rows d, k=t) from VTs
    const int m = w * 16 + (lane & 15);
    bf16x8 afm[2];
#pragma unroll
    for (int kk = 0; kk < 2; ++kk)
#pragma unroll
      for (int e = 0; e < 8; ++e) {
        const int t = kk * 32 + (lane >> 4) * 8 + e;
        afm[kk][e] = (short)Os[t * 64 + (((m >> 3) ^ (t & 7)) << 3) + (m & 7)];
      }
    f32x4 acckv[4] = {};
#pragma unroll
    for (int j = 0; j < 4; ++j)
#pragma unroll
      for (int kk = 0; kk < 2; ++kk)
        acckv[j] = __builtin_amdgcn_mfma_f32_16x16x32_bf16(
            afm[kk], frag64(VTs, j * 16 + (lane & 15), kk * 4 + (lane >> 4)), acckv[j], 0, 0, 0);
    unsigned short* dkv = kvt + ((unsigned)h * NCH + c) * 4096u;
#pragma unroll
    for (int j = 0; j < 4; ++j) {
      const int d = j * 16 + (lane & 15);
      const int mq = w * 16 + (lane >> 4) * 4;
      u16x4 o;
#pragma unroll
      for (int r = 0; r < 4; ++r) o[r] = f2bf(acckv[j][r]);
      *reinterpret_cast<u16x4*>(&dkv[(unsigned)d * 64 + mq]) = o;
    }
  }
}

// ---------------- Kernel 4: exclusive prefix over chunks (parallel) --------
__global__ __launch_bounds__(256) void k_prefix(const unsigned short* __restrict__ kvt,
                                                const float* __restrict__ ksum,
                                                unsigned short* __restrict__ st,
                                                float* __restrict__ z) {
  const int h = blockIdx.y;
  const unsigned e = blockIdx.x * 256u + threadIdx.x;
  float run = 0.f;
#pragma unroll
  for (int c = 0; c < NCH; ++c) {
    const unsigned idx = ((unsigned)h * NCH + c) * 4096u + e;
    st[idx] = f2bf(run);
    run += bf2f(kvt[idx]);
  }
  if (blockIdx.x == 0 && threadIdx.x < 64) {
    float zr = 0.f;
#pragma unroll
    for (int c = 0; c < NCH; ++c) {
      const unsigned idx = ((unsigned)h * NCH + c) * 64u + threadIdx.x;
      z[idx] = zr;
      zr += ksum[idx];
    }
  }
}

// ---------------- Kernel 5: per-(h,c) intra-chunk attention (MFMA) ---------
__global__ __launch_bounds__(256) void k_attn(const unsigned short* __restrict__ qp,
                                              const unsigned short* __restrict__ kp,
                                              const unsigned short* __restrict__ vt,
                                              const unsigned short* __restrict__ st,
                                              const float* __restrict__ z,
                                              unsigned short* __restrict__ attnb) {
  __shared__ unsigned short QPs[4096];
  __shared__ unsigned short KPs[4096];  // reused as A^bf16 after phase A
  __shared__ unsigned short VTs[4096];
  __shared__ unsigned short STs[4096];
  __shared__ float zsm[64];
  __shared__ float nsm[64];
  const int tid = threadIdx.x, lane = tid & 63, w = tid >> 6;
  const int c = blockIdx.x, h = blockIdx.y;
  stage_tile64(qp + ((unsigned)h * TT + c * 64) * 64, 64, QPs, w, lane);
  stage_tile64(kp + ((unsigned)h * TT + c * 64) * 64, 64, KPs, w, lane);
  stage_tile64(vt + (unsigned)h * 64 * TT + (unsigned)c * 64, TT, VTs, w, lane);
  stage_tile64(st + ((unsigned)h * NCH + c) * 4096u, 64, STs, w, lane);
  if (tid < 64) zsm[tid] = z[((unsigned)h * NCH + c) * 64u + tid];
  __syncthreads();
  const int tr = w * 16 + (lane & 15);
  bf16x8 afq[2];
#pragma unroll
  for (int kk = 0; kk < 2; ++kk) afq[kk] = frag64(QPs, tr, kk * 4 + (lane >> 4));
  f32x4 accA[4] = {};
#pragma unroll
  for (int j = 0; j < 4; ++j)
#pragma unroll
    for (int kk = 0; kk < 2; ++kk)
      accA[j] = __builtin_amdgcn_mfma_f32_16x16x32_bf16(
          afq[kk], frag64(KPs, j * 16 + (lane & 15), kk * 4 + (lane >> 4)), accA[j], 0, 0, 0);
  float rs[4] = {0.f, 0.f, 0.f, 0.f};
#pragma unroll
  for (int j = 0; j < 4; ++j) {
    const int s = j * 16 + (lane & 15);
#pragma unroll
    for (int r = 0; r < 4; ++r) {
      const int t = w * 16 + (lane >> 4) * 4 + r;
      float v = (s <= t) ? accA[j][r] : 0.f;
      accA[j][r] = v;
      rs[r] += v;
    }
  }
#pragma unroll
  for (int r = 0; r < 4; ++r)
#pragma unroll
    for (int off = 1; off < 16; off <<= 1) rs[r] += __shfl_xor(rs[r], off, 64);
  __syncthreads();
  if ((lane & 15) == 0) {
#pragma unroll
    for (int r = 0; r < 4; ++r) nsm[w * 16 + (lane >> 4) * 4 + r] = rs[r];
  }
#pragma unroll
  for (int j = 0; j < 4; ++j) {
    const int s = j * 16 + (lane & 15);
#pragma unroll
    for (int r = 0; r < 4; ++r) {
      const int t = w * 16 + (lane >> 4) * 4 + r;
      KPs[t * 64 + (((s >> 3) ^ (t & 7)) * 8) + (s & 7)] = f2bf(accA[j][r]);
    }
  }
  __syncthreads();
  {
    const int t = tid >> 2, part = tid & 3;
    float qz = 0.f;
#pragma unroll
    for (int mm = 0; mm < 16; ++mm) {
      const int m = part * 16 + mm;
      qz += bf2f(QPs[t * 64 + (((m >> 3) ^ (t & 7)) * 8) + (m & 7)]) * zsm[m];
    }
    qz += __shfl_xor(qz, 1, 64);
    qz += __shfl_xor(qz, 2, 64);
    if (part == 0) nsm[t] += qz + EPSV;
  }
  bf16x8 afa[2];
#pragma unroll
  for (int kk = 0; kk < 2; ++kk) afa[kk] = frag64(KPs, tr, kk * 4 + (lane >> 4));
  f32x4 acc[4] = {};
#pragma unroll
  for (int j = 0; j < 4; ++j) {
    const int br = j * 16 + (lane & 15);
#pragma unroll
    for (int kk = 0; kk < 2; ++kk) {
      acc[j] = __builtin_amdgcn_mfma_f32_16x16x32_bf16(
          afa[kk], frag64(VTs, br, kk * 4 + (lane >> 4)), acc[j], 0, 0, 0);
      acc[j] = __builtin_amdgcn_mfma_f32_16x16x32_bf16(
          afq[kk], frag64(STs, br, kk * 4 + (lane >> 4)), acc[j], 0, 0, 0);
    }
  }
  __syncthreads();
#pragma unroll
  for (int j = 0; j < 4; ++j) {
    const int d = j * 16 + (lane & 15);
#pragma unroll
    for (int r = 0; r < 4; ++r) {
      const int t = w * 16 + (lane >> 4) * 4 + r;
      attnb[(unsigned)(c * 64 + t) * CC + h * 64 + d] = f2bf(acc[j][r] / nsm[t]);
    }
  }
}

// ---------------- Kernel 6: out = attn @ w_out + b (64x64 tiles, 2/CU) -----
__global__ __launch_bounds__(256) void k_out_mfma(const unsigned short* __restrict__ Abf,
                                                  const unsigned short* __restrict__ WoT,
                                                  const float* __restrict__ bias,
                                                  float* __restrict__ out) {
  __shared__ unsigned short As[4096];  // 64 x 64
  __shared__ unsigned short Bs[4096];  // 64 x 64
  const int tid = threadIdx.x, lane = tid & 63, w = tid >> 6;
  const int wm = w >> 1, wn = w & 1;   // 2M x 2N, 32x32 per warp
  // XCD-aware bijective swizzle (nwg = 16*32 = 512, cpx=64)
  int lin = blockIdx.y * 16 + blockIdx.x;
  int swz = (lin & 7) * 64 + (lin >> 3);
  const int bx = swz & 15, by = swz >> 4;
  const int m0 = by * 64, n0 = bx * 64;
  const int l8 = lane >> 3, l7 = lane & 7;
  const int kcg = (l7 ^ l8) * 8;
  f32x4 acc[2][2] = {};
  for (int k0 = 0; k0 < CC; k0 += 64) {
    if (k0) __syncthreads();
#pragma unroll
    for (int jj = 0; jj < 2; ++jj) {
      const int inst = w * 2 + jj;
      const int row = inst * 8 + l8;
      gload16(&Abf[(unsigned)(m0 + row) * CC + k0 + kcg], &As[inst * 512]);
      gload16(&WoT[(unsigned)(n0 + row) * CC + k0 + kcg], &Bs[inst * 512]);
    }
    __syncthreads();
#pragma unroll
    for (int kk = 0; kk < 2; ++kk) {
      bf16x8 af[2], bg[2];
#pragma unroll
      for (int i = 0; i < 2; ++i) {
        const int r = wm * 32 + i * 16 + (lane & 15);
        const int slot = (kk * 4 + (lane >> 4)) ^ (r & 7);
        af[i] = *reinterpret_cast<const bf16x8*>(&As[r * 64 + slot * 8]);
      }
#pragma unroll
      for (int j = 0; j < 2; ++j) {
        const int r = wn * 32 + j * 16 + (lane & 15);
        const int slot = (kk * 4 + (lane >> 4)) ^ (r & 7);
        bg[j] = *reinterpret_cast<const bf16x8*>(&Bs[r * 64 + slot * 8]);
      }
#pragma unroll
      for (int i = 0; i < 2; ++i)
#pragma unroll
        for (int j = 0; j < 2; ++j)
          acc[i][j] = __builtin_amdgcn_mfma_f32_16x16x32_bf16(af[i], bg[j],
                                                              acc[i][j], 0, 0, 0);
    }
  }
#pragma unroll
  for (int i = 0; i < 2; ++i) {
#pragma unroll
    for (int j = 0; j < 2; ++j) {
      const int n = n0 + wn * 32 + j * 16 + (lane & 15);
      const float bv = bias[n];
#pragma unroll
      for (int r = 0; r < 4; ++r) {
        const int m = m0 + wm * 32 + i * 16 + (lane >> 4) * 4 + r;
        out[(unsigned)m * CC + n] = acc[i][j][r] + bv;
      }
    }
  }
}

extern "C" void kernel_launch(void* const* d_in, const int* in_sizes, int n_in,
                              void* d_out, int out_size, void* d_ws, size_t ws_size,
                              hipStream_t stream) {
  const float* x = (const float*)d_in[0];
  const float* w_qkv = (const float*)d_in[1];
  const float* b_qkv = (const float*)d_in[2];
  const float* w_out = (const float*)d_in[3];
  const float* b_out = (const float*)d_in[4];
  const float* proj = (const float*)d_in[5];
  float* ws = (float*)d_ws;
  float* out = (float*)d_out;
  float* ksum = ws + OFF_KS;
  float* zf = ws + OFF_Z;
  unsigned short* ub = (unsigned short*)(ws + OFF_U16);
  unsigned short* kvt = ub + U_KVT;
  unsigned short* qbf = ub + U_QBF;
  unsigned short* kbf = ub + U_KBF;
  unsigned short* vt = ub + U_VT;
  unsigned short* qp = ub + U_QP;
  unsigned short* kp = ub + U_KP;
  unsigned short* st = ub + U_ST;
  unsigned short* xbf = ub + U_XBF;
  unsigned short* wqT = ub + U_WQT;
  unsigned short* woT = ub + U_WOT;
  unsigned short* attnb = xbf;  // alias: x_bf16 dead after k_qkv_mfma
  dim3 blk(256, 1, 1);
  k_prep<<<dim3(3072), blk, 0, stream>>>(x, w_qkv, w_out, xbf, wqT, woT);
  k_qkv_mfma<<<dim3(N_QKV / 128, TT / 64), blk, 0, stream>>>(xbf, wqT, b_qkv, qbf, kbf, vt);
  k_feat<<<dim3(NCH, HH, 2), blk, 0, stream>>>(proj, qbf, kbf, vt, qp, kp, kvt, ksum);
  k_prefix<<<dim3(16, HH), blk, 0, stream>>>(kvt, ksum, st, zf);
  k_attn<<<dim3(NCH, HH), blk, 0, stream>>>(qp, kp, vt, st, zf, attnb);
  k_out_mfma<<<dim3(CC / 64, TT / 64), blk, 0, stream>>>(attnb, woT, b_out, out);
}

// Round 9
// 68.922 us; speedup vs baseline: 1.3706x; 1.0233x over previous
//
#include <hip/hip_runtime.h>
#include <hip/hip_bf16.h>

#define TT 2048
#define CC 1024
#define HH 16
#define DD 64
#define FM 64
#define NCH 32
#define CL 64
#define N_QKV 3072
#define EPSV 1e-6f

// fp32 workspace region (float units)
#define OFF_KS  0u          // Ksum fp32 [16][32][64m]
#define OFF_Z   32768u      // z fp32 [16][32][64m]
#define OFF_U16 65536u      // bf16 region start (float units)
// bf16 region offsets (ushort units)
#define U_KVT 0u            // KV^T bf16 [16][32][64d][64m]
#define U_PROJT 2097152u    // projT bf16 [16][64m][64d]
#define U_VT  6291456u      // v^T bf16 [16][64][2048]
#define U_QP  8388608u      // q' bf16 [16][2048][64m]
#define U_KP  10485760u     // k' bf16 [16][2048][64m]
#define U_ST  12582912u     // S^T bf16 [16][32][64d][64m]
#define U_XBF 14680064u     // x bf16 (later aliased as attnb)
#define U_WQT 16777216u     // w_qkv^T bf16 [3072][1024]
#define U_WOT 19922944u     // w_out^T bf16 [1024][1024]

typedef __attribute__((ext_vector_type(8))) short bf16x8;
typedef __attribute__((ext_vector_type(4))) float f32x4;
typedef __attribute__((ext_vector_type(4))) unsigned short u16x4;

__device__ __forceinline__ unsigned short f2bf(float f) {
  unsigned int u = __float_as_uint(f);
  u = (u + 0x7fffu + ((u >> 16) & 1u)) >> 16;
  return (unsigned short)u;
}
__device__ __forceinline__ float bf2f(unsigned short b) {
  return __uint_as_float(((unsigned)b) << 16);
}

__device__ __forceinline__ void gload16(const void* g, void* l) {
  __builtin_amdgcn_global_load_lds(
      (const __attribute__((address_space(1))) unsigned int*)g,
      (__attribute__((address_space(3))) unsigned int*)l, 16, 0, 0);
}

// stage a 64-row x 64-ushort (8KB) tile into LDS, XOR-swizzled (chunk^=row&7)
__device__ __forceinline__ void stage_tile64(const unsigned short* g, unsigned rowstride,
                                             unsigned short* lds, int w, int lane) {
  const int l8 = lane >> 3, l7 = lane & 7;
  const int kcg = (l7 ^ l8) * 8;
#pragma unroll
  for (int jj = 0; jj < 2; ++jj) {
    const int inst = w * 2 + jj;
    const int row = inst * 8 + l8;
    gload16(&g[(unsigned)row * rowstride + kcg], &lds[inst * 512]);
  }
}

// read an 8-element bf16 fragment from a swizzled 64x64 LDS tile
__device__ __forceinline__ bf16x8 frag64(const unsigned short* lds, int r, int kchunk) {
  const int slot = kchunk ^ (r & 7);
  return *reinterpret_cast<const bf16x8*>(&lds[r * 64 + slot * 8]);
}

// ---------------- Kernel 0: fused prep (xconv + transposes + projT) --------
__device__ __forceinline__ void transpose64_dev(const float* __restrict__ src,
                                                unsigned short* __restrict__ dst,
                                                int K, int N, int k0, int n0,
                                                float (*T)[68], int tid) {
#pragma unroll
  for (int it = 0; it < 4; ++it) {
    int f = tid + it * 256;
    int r = f >> 4, c4 = (f & 15) * 4;
    float4 v = *reinterpret_cast<const float4*>(&src[(unsigned)(k0 + r) * N + n0 + c4]);
    T[r][c4 + 0] = v.x; T[r][c4 + 1] = v.y;
    T[r][c4 + 2] = v.z; T[r][c4 + 3] = v.w;
  }
  __syncthreads();
#pragma unroll
  for (int it = 0; it < 4; ++it) {
    int f = tid + it * 256;
    int nl = f >> 4, kq = (f & 15) * 4;
    u16x4 o;
#pragma unroll
    for (int j = 0; j < 4; ++j) o[j] = f2bf(T[kq + j][nl]);
    *reinterpret_cast<u16x4*>(&dst[(unsigned)(n0 + nl) * K + k0 + kq]) = o;
  }
}

__global__ __launch_bounds__(256) void k_prep(const float* __restrict__ x,
                                              const float* __restrict__ wq,
                                              const float* __restrict__ wo,
                                              const float* __restrict__ proj,
                                              unsigned short* __restrict__ xbf,
                                              unsigned short* __restrict__ wqT,
                                              unsigned short* __restrict__ woT,
                                              unsigned short* __restrict__ projT) {
  __shared__ float T[64][68];
  const int tid = threadIdx.x;
  int b = blockIdx.x;
  if (b < 2048) {  // x f32 -> bf16
    unsigned i = (unsigned)b * 1024u + (unsigned)tid * 4u;
    float4 v = *reinterpret_cast<const float4*>(&x[i]);
    u16x4 o;
    o[0] = f2bf(v.x); o[1] = f2bf(v.y); o[2] = f2bf(v.z); o[3] = f2bf(v.w);
    *reinterpret_cast<u16x4*>(&xbf[i]) = o;
    return;
  }
  b -= 2048;
  if (b < 768) {  // w_qkv [1024][3072] -> wqT [3072][1024]
    transpose64_dev(wq, wqT, CC, N_QKV, (b / 48) * 64, (b % 48) * 64, T, tid);
    return;
  }
  b -= 768;
  if (b < 256) {  // w_out [1024][1024] -> woT [1024][1024]
    transpose64_dev(wo, woT, CC, CC, (b / 16) * 64, (b % 16) * 64, T, tid);
    return;
  }
  b -= 256;  // proj [h][64d][64m] -> projT [h][64m][64d]
  transpose64_dev(proj + (unsigned)b * 4096u, projT + (unsigned)b * 4096u, 64, 64, 0, 0, T, tid);
}

// ---------------- Kernel 1: qkv GEMM + fused feature map -------------------
// q/k warps: p' = relu(tile @ projT)/8 computed in-epilogue -> qp/kp [h][t][m]
// v warps: vT bf16 [h][d][t]
__global__ __launch_bounds__(256) void k_qkv_mfma(const unsigned short* __restrict__ Xbf,
                                                  const unsigned short* __restrict__ WqT,
                                                  const float* __restrict__ bias,
                                                  const unsigned short* __restrict__ projT,
                                                  unsigned short* __restrict__ qp,
                                                  unsigned short* __restrict__ kp,
                                                  unsigned short* __restrict__ vt) {
  __shared__ unsigned short LDSU[12288];  // As 64x64 | Bs 128x64 ; epilogue: 4x 32x64
  unsigned short* As = LDSU;
  unsigned short* Bs = LDSU + 4096;
  const int tid = threadIdx.x, lane = tid & 63, w = tid >> 6;
  const int wm = w >> 1, wn = w & 1;   // 2M x 2N warp layout (32 x 64 per warp)
  // XCD-aware bijective swizzle: nwg = 24*32 = 768, 768%8==0, cpx=96
  int lin = blockIdx.y * 24 + blockIdx.x;
  int swz = (lin & 7) * 96 + (lin >> 3);
  const int bx = swz % 24, by = swz / 24;
  const int m0b = by * 64, n0b = bx * 128;
  const int l8 = lane >> 3, l7 = lane & 7;
  const int kcg = (l7 ^ l8) * 8;
  f32x4 acc[2][4] = {};
  for (int k0 = 0; k0 < CC; k0 += 64) {
    if (k0) __syncthreads();
#pragma unroll
    for (int jj = 0; jj < 2; ++jj) {   // A: 64x64
      const int inst = w * 2 + jj;
      const int row = inst * 8 + l8;
      gload16(&Xbf[(unsigned)(m0b + row) * CC + k0 + kcg], &As[inst * 512]);
    }
#pragma unroll
    for (int jj = 0; jj < 4; ++jj) {   // B: 128x64
      const int inst = w * 4 + jj;
      const int row = inst * 8 + l8;
      gload16(&WqT[(unsigned)(n0b + row) * CC + k0 + kcg], &Bs[inst * 512]);
    }
    __syncthreads();
#pragma unroll
    for (int kk = 0; kk < 2; ++kk) {
      bf16x8 af[2], bg[4];
#pragma unroll
      for (int i = 0; i < 2; ++i) {
        const int r = wm * 32 + i * 16 + (lane & 15);
        const int slot = (kk * 4 + (lane >> 4)) ^ (r & 7);
        af[i] = *reinterpret_cast<const bf16x8*>(&As[r * 64 + slot * 8]);
      }
#pragma unroll
      for (int j = 0; j < 4; ++j) {
        const int r = wn * 64 + j * 16 + (lane & 15);
        const int slot = (kk * 4 + (lane >> 4)) ^ (r & 7);
        bg[j] = *reinterpret_cast<const bf16x8*>(&Bs[r * 64 + slot * 8]);
      }
#pragma unroll
      for (int i = 0; i < 2; ++i)
#pragma unroll
        for (int j = 0; j < 4; ++j)
          acc[i][j] = __builtin_amdgcn_mfma_f32_16x16x32_bf16(af[i], bg[j],
                                                              acc[i][j], 0, 0, 0);
    }
  }
  const int n0w = n0b + wn * 64;       // one (sel,h) per warp (block-uniform sel)
  const int sel = n0w >> 10;
  const int h = (n0w & 1023) >> 6;
  const int t0w = m0b + wm * 32;
  float bvj[4];
#pragma unroll
  for (int j = 0; j < 4; ++j) bvj[j] = bias[n0w + j * 16 + (lane & 15)];
  __syncthreads();  // all MFMA reads of LDSU done
  // stage warp's 32t x 64d tile (+bias, bf16) into private quadrant, swizzled
  unsigned short* myT = LDSU + w * 2048;
#pragma unroll
  for (int i = 0; i < 2; ++i)
#pragma unroll
    for (int j = 0; j < 4; ++j) {
      const int d = j * 16 + (lane & 15);
#pragma unroll
      for (int r = 0; r < 4; ++r) {
        const int t = i * 16 + (lane >> 4) * 4 + r;
        myT[t * 64 + (((d >> 3) ^ (t & 7)) << 3) + (d & 7)] = f2bf(acc[i][j][r] + bvj[j]);
      }
    }
  if (sel == 2) {
    // vT [h][d][t]: per lane 4x bf16x8 along t (64B-line writes)
#pragma unroll
    for (int q = 0; q < 4; ++q) {
      const int cid = q * 64 + lane;
      const int d = cid >> 2, tc = cid & 3;
      bf16x8 o;
#pragma unroll
      for (int e = 0; e < 8; ++e) {
        const int t = tc * 8 + e;
        o[e] = (short)myT[t * 64 + (((d >> 3) ^ (t & 7)) << 3) + (d & 7)];
      }
      *reinterpret_cast<bf16x8*>(&vt[((unsigned)h * 64 + d) * TT + t0w + tc * 8]) = o;
    }
    return;
  }
  // fused feature map: p'[t][m] = relu(sum_d tile[t][d] projT[h][m][d]) / 8
  const unsigned short* pjt = projT + (unsigned)h * 4096u;
  bf16x8 aq[2][2], bp[4][2];
#pragma unroll
  for (int jm = 0; jm < 4; ++jm)
#pragma unroll
    for (int kk = 0; kk < 2; ++kk)
      bp[jm][kk] = *reinterpret_cast<const bf16x8*>(
          &pjt[(unsigned)(jm * 16 + (lane & 15)) * 64 + kk * 32 + (lane >> 4) * 8]);
#pragma unroll
  for (int i = 0; i < 2; ++i)
#pragma unroll
    for (int kk = 0; kk < 2; ++kk)
      aq[i][kk] = frag64(myT, i * 16 + (lane & 15), kk * 4 + (lane >> 4));
  f32x4 accp[2][4] = {};
#pragma unroll
  for (int i = 0; i < 2; ++i)
#pragma unroll
    for (int jm = 0; jm < 4; ++jm)
#pragma unroll
      for (int kk = 0; kk < 2; ++kk)
        accp[i][jm] = __builtin_amdgcn_mfma_f32_16x16x32_bf16(aq[i][kk], bp[jm][kk],
                                                              accp[i][jm], 0, 0, 0);
  // relu/8 + restage p' into myT as [t][m] swizzled (warp-private, in-order DS)
#pragma unroll
  for (int i = 0; i < 2; ++i)
#pragma unroll
    for (int jm = 0; jm < 4; ++jm) {
      const int m = jm * 16 + (lane & 15);
#pragma unroll
      for (int r = 0; r < 4; ++r) {
        const int t = i * 16 + (lane >> 4) * 4 + r;
        float v = accp[i][jm][r];
        v = (v > 0.f ? v : 0.f) * 0.125f;
        myT[t * 64 + (((m >> 3) ^ (t & 7)) << 3) + (m & 7)] = f2bf(v);
      }
    }
  // coalesced store: q'/k' [h][t][m], 1KB per store instruction
  unsigned short* dst0 = (sel ? kp : qp) + ((unsigned)h * TT + (unsigned)t0w) * 64u;
#pragma unroll
  for (int q = 0; q < 4; ++q) {
    const int cid = q * 64 + lane;
    const int t = cid >> 3, mc = cid & 7;
    bf16x8 o = *reinterpret_cast<const bf16x8*>(&myT[t * 64 + ((mc ^ (t & 7)) << 3)]);
    *reinterpret_cast<bf16x8*>(&dst0[(unsigned)cid * 8]) = o;
  }
}

// ---------------- Kernel 2: per-chunk KV^T[d][m] + Ksum (MFMA) -------------
__global__ __launch_bounds__(256) void k_chunkkv(const unsigned short* __restrict__ kp,
                                                 const unsigned short* __restrict__ vt,
                                                 unsigned short* __restrict__ kvt,
                                                 float* __restrict__ ksum) {
  __shared__ unsigned short Xs[4096];
  __shared__ unsigned short VTs[4096];
  const int tid = threadIdx.x, lane = tid & 63, w = tid >> 6;
  const int c = blockIdx.x, h = blockIdx.y;
  stage_tile64(kp + ((unsigned)h * TT + c * 64) * 64, 64, Xs, w, lane);
  stage_tile64(vt + (unsigned)h * 64 * TT + (unsigned)c * 64, TT, VTs, w, lane);
  __syncthreads();
  // A-frags (rows m, k=t) gathered from swizzled Xs [t][m]
  const int m = w * 16 + (lane & 15);
  bf16x8 afm[2];
  float ks = 0.f;
#pragma unroll
  for (int kk = 0; kk < 2; ++kk)
#pragma unroll
    for (int e = 0; e < 8; ++e) {
      const int t = kk * 32 + (lane >> 4) * 8 + e;
      unsigned short u = Xs[t * 64 + (((m >> 3) ^ (t & 7)) << 3) + (m & 7)];
      afm[kk][e] = (short)u;
      ks += bf2f(u);
    }
  ks += __shfl_xor(ks, 16, 64);
  ks += __shfl_xor(ks, 32, 64);
  if (lane < 16) ksum[((unsigned)h * NCH + c) * 64u + m] = ks;
  f32x4 acckv[4] = {};
#pragma unroll
  for (int j = 0; j < 4; ++j)
#pragma unroll
    for (int kk = 0; kk < 2; ++kk)
      acckv[j] = __builtin_amdgcn_mfma_f32_16x16x32_bf16(
          afm[kk], frag64(VTs, j * 16 + (lane & 15), kk * 4 + (lane >> 4)), acckv[j], 0, 0, 0);
  unsigned short* dkv = kvt + ((unsigned)h * NCH + c) * 4096u;
#pragma unroll
  for (int j = 0; j < 4; ++j) {
    const int d = j * 16 + (lane & 15);
    const int mq = w * 16 + (lane >> 4) * 4;
    u16x4 o;
#pragma unroll
    for (int r = 0; r < 4; ++r) o[r] = f2bf(acckv[j][r]);
    *reinterpret_cast<u16x4*>(&dkv[(unsigned)d * 64 + mq]) = o;
  }
}

// ---------------- Kernel 4: exclusive prefix over chunks (parallel) --------
__global__ __launch_bounds__(256) void k_prefix(const unsigned short* __restrict__ kvt,
                                                const float* __restrict__ ksum,
                                                unsigned short* __restrict__ st,
                                                float* __restrict__ z) {
  const int h = blockIdx.y;
  const unsigned e = blockIdx.x * 256u + threadIdx.x;
  float run = 0.f;
#pragma unroll
  for (int c = 0; c < NCH; ++c) {
    const unsigned idx = ((unsigned)h * NCH + c) * 4096u + e;
    st[idx] = f2bf(run);
    run += bf2f(kvt[idx]);
  }
  if (blockIdx.x == 0 && threadIdx.x < 64) {
    float zr = 0.f;
#pragma unroll
    for (int c = 0; c < NCH; ++c) {
      const unsigned idx = ((unsigned)h * NCH + c) * 64u + threadIdx.x;
      z[idx] = zr;
      zr += ksum[idx];
    }
  }
}

// ---------------- Kernel 5: per-(h,c) intra-chunk attention (MFMA) ---------
__global__ __launch_bounds__(256) void k_attn(const unsigned short* __restrict__ qp,
                                              const unsigned short* __restrict__ kp,
                                              const unsigned short* __restrict__ vt,
                                              const unsigned short* __restrict__ st,
                                              const float* __restrict__ z,
                                              unsigned short* __restrict__ attnb) {
  __shared__ unsigned short QPs[4096];
  __shared__ unsigned short KPs[4096];  // reused as A^bf16 after phase A
  __shared__ unsigned short VTs[4096];
  __shared__ unsigned short STs[4096];
  __shared__ float zsm[64];
  __shared__ float nsm[64];
  const int tid = threadIdx.x, lane = tid & 63, w = tid >> 6;
  const int c = blockIdx.x, h = blockIdx.y;
  stage_tile64(qp + ((unsigned)h * TT + c * 64) * 64, 64, QPs, w, lane);
  stage_tile64(kp + ((unsigned)h * TT + c * 64) * 64, 64, KPs, w, lane);
  stage_tile64(vt + (unsigned)h * 64 * TT + (unsigned)c * 64, TT, VTs, w, lane);
  stage_tile64(st + ((unsigned)h * NCH + c) * 4096u, 64, STs, w, lane);
  if (tid < 64) zsm[tid] = z[((unsigned)h * NCH + c) * 64u + tid];
  __syncthreads();
  const int tr = w * 16 + (lane & 15);
  bf16x8 afq[2];
#pragma unroll
  for (int kk = 0; kk < 2; ++kk) afq[kk] = frag64(QPs, tr, kk * 4 + (lane >> 4));
  f32x4 accA[4] = {};
#pragma unroll
  for (int j = 0; j < 4; ++j)
#pragma unroll
    for (int kk = 0; kk < 2; ++kk)
      accA[j] = __builtin_amdgcn_mfma_f32_16x16x32_bf16(
          afq[kk], frag64(KPs, j * 16 + (lane & 15), kk * 4 + (lane >> 4)), accA[j], 0, 0, 0);
  float rs[4] = {0.f, 0.f, 0.f, 0.f};
#pragma unroll
  for (int j = 0; j < 4; ++j) {
    const int s = j * 16 + (lane & 15);
#pragma unroll
    for (int r = 0; r < 4; ++r) {
      const int t = w * 16 + (lane >> 4) * 4 + r;
      float v = (s <= t) ? accA[j][r] : 0.f;
      accA[j][r] = v;
      rs[r] += v;
    }
  }
#pragma unroll
  for (int r = 0; r < 4; ++r)
#pragma unroll
    for (int off = 1; off < 16; off <<= 1) rs[r] += __shfl_xor(rs[r], off, 64);
  __syncthreads();
  if ((lane & 15) == 0) {
#pragma unroll
    for (int r = 0; r < 4; ++r) nsm[w * 16 + (lane >> 4) * 4 + r] = rs[r];
  }
#pragma unroll
  for (int j = 0; j < 4; ++j) {
    const int s = j * 16 + (lane & 15);
#pragma unroll
    for (int r = 0; r < 4; ++r) {
      const int t = w * 16 + (lane >> 4) * 4 + r;
      KPs[t * 64 + (((s >> 3) ^ (t & 7)) * 8) + (s & 7)] = f2bf(accA[j][r]);
    }
  }
  __syncthreads();
  {
    const int t = tid >> 2, part = tid & 3;
    float qz = 0.f;
#pragma unroll
    for (int mm = 0; mm < 16; ++mm) {
      const int m = part * 16 + mm;
      qz += bf2f(QPs[t * 64 + (((m >> 3) ^ (t & 7)) * 8) + (m & 7)]) * zsm[m];
    }
    qz += __shfl_xor(qz, 1, 64);
    qz += __shfl_xor(qz, 2, 64);
    if (part == 0) nsm[t] += qz + EPSV;
  }
  bf16x8 afa[2];
#pragma unroll
  for (int kk = 0; kk < 2; ++kk) afa[kk] = frag64(KPs, tr, kk * 4 + (lane >> 4));
  f32x4 acc[4] = {};
#pragma unroll
  for (int j = 0; j < 4; ++j) {
    const int br = j * 16 + (lane & 15);
#pragma unroll
    for (int kk = 0; kk < 2; ++kk) {
      acc[j] = __builtin_amdgcn_mfma_f32_16x16x32_bf16(
          afa[kk], frag64(VTs, br, kk * 4 + (lane >> 4)), acc[j], 0, 0, 0);
      acc[j] = __builtin_amdgcn_mfma_f32_16x16x32_bf16(
          afq[kk], frag64(STs, br, kk * 4 + (lane >> 4)), acc[j], 0, 0, 0);
    }
  }
  __syncthreads();
#pragma unroll
  for (int j = 0; j < 4; ++j) {
    const int d = j * 16 + (lane & 15);
#pragma unroll
    for (int r = 0; r < 4; ++r) {
      const int t = w * 16 + (lane >> 4) * 4 + r;
      attnb[(unsigned)(c * 64 + t) * CC + h * 64 + d] = f2bf(acc[j][r] / nsm[t]);
    }
  }
}

// ---------------- Kernel 6: out = attn @ w_out + b (64x64 tiles, 2/CU) -----
__global__ __launch_bounds__(256) void k_out_mfma(const unsigned short* __restrict__ Abf,
                                                  const unsigned short* __restrict__ WoT,
                                                  const float* __restrict__ bias,
                                                  float* __restrict__ out) {
  __shared__ unsigned short As[4096];  // 64 x 64
  __shared__ unsigned short Bs[4096];  // 64 x 64
  const int tid = threadIdx.x, lane = tid & 63, w = tid >> 6;
  const int wm = w >> 1, wn = w & 1;   // 2M x 2N, 32x32 per warp
  // XCD-aware bijective swizzle (nwg = 16*32 = 512, cpx=64)
  int lin = blockIdx.y * 16 + blockIdx.x;
  int swz = (lin & 7) * 64 + (lin >> 3);
  const int bx = swz & 15, by = swz >> 4;
  const int m0 = by * 64, n0 = bx * 64;
  const int l8 = lane >> 3, l7 = lane & 7;
  const int kcg = (l7 ^ l8) * 8;
  f32x4 acc[2][2] = {};
  for (int k0 = 0; k0 < CC; k0 += 64) {
    if (k0) __syncthreads();
#pragma unroll
    for (int jj = 0; jj < 2; ++jj) {
      const int inst = w * 2 + jj;
      const int row = inst * 8 + l8;
      gload16(&Abf[(unsigned)(m0 + row) * CC + k0 + kcg], &As[inst * 512]);
      gload16(&WoT[(unsigned)(n0 + row) * CC + k0 + kcg], &Bs[inst * 512]);
    }
    __syncthreads();
#pragma unroll
    for (int kk = 0; kk < 2; ++kk) {
      bf16x8 af[2], bg[2];
#pragma unroll
      for (int i = 0; i < 2; ++i) {
        const int r = wm * 32 + i * 16 + (lane & 15);
        const int slot = (kk * 4 + (lane >> 4)) ^ (r & 7);
        af[i] = *reinterpret_cast<const bf16x8*>(&As[r * 64 + slot * 8]);
      }
#pragma unroll
      for (int j = 0; j < 2; ++j) {
        const int r = wn * 32 + j * 16 + (lane & 15);
        const int slot = (kk * 4 + (lane >> 4)) ^ (r & 7);
        bg[j] = *reinterpret_cast<const bf16x8*>(&Bs[r * 64 + slot * 8]);
      }
#pragma unroll
      for (int i = 0; i < 2; ++i)
#pragma unroll
        for (int j = 0; j < 2; ++j)
          acc[i][j] = __builtin_amdgcn_mfma_f32_16x16x32_bf16(af[i], bg[j],
                                                              acc[i][j], 0, 0, 0);
    }
  }
#pragma unroll
  for (int i = 0; i < 2; ++i) {
#pragma unroll
    for (int j = 0; j < 2; ++j) {
      const int n = n0 + wn * 32 + j * 16 + (lane & 15);
      const float bv = bias[n];
#pragma unroll
      for (int r = 0; r < 4; ++r) {
        const int m = m0 + wm * 32 + i * 16 + (lane >> 4) * 4 + r;
        out[(unsigned)m * CC + n] = acc[i][j][r] + bv;
      }
    }
  }
}

extern "C" void kernel_launch(void* const* d_in, const int* in_sizes, int n_in,
                              void* d_out, int out_size, void* d_ws, size_t ws_size,
                              hipStream_t stream) {
  const float* x = (const float*)d_in[0];
  const float* w_qkv = (const float*)d_in[1];
  const float* b_qkv = (const float*)d_in[2];
  const float* w_out = (const float*)d_in[3];
  const float* b_out = (const float*)d_in[4];
  const float* proj = (const float*)d_in[5];
  float* ws = (float*)d_ws;
  float* out = (float*)d_out;
  float* ksum = ws + OFF_KS;
  float* zf = ws + OFF_Z;
  unsigned short* ub = (unsigned short*)(ws + OFF_U16);
  unsigned short* kvt = ub + U_KVT;
  unsigned short* projT = ub + U_PROJT;
  unsigned short* vt = ub + U_VT;
  unsigned short* qp = ub + U_QP;
  unsigned short* kp = ub + U_KP;
  unsigned short* st = ub + U_ST;
  unsigned short* xbf = ub + U_XBF;
  unsigned short* wqT = ub + U_WQT;
  unsigned short* woT = ub + U_WOT;
  unsigned short* attnb = xbf;  // alias: x_bf16 dead after k_qkv_mfma
  dim3 blk(256, 1, 1);
  k_prep<<<dim3(3088), blk, 0, stream>>>(x, w_qkv, w_out, proj, xbf, wqT, woT, projT);
  k_qkv_mfma<<<dim3(N_QKV / 128, TT / 64), blk, 0, stream>>>(xbf, wqT, b_qkv, projT,
                                                             qp, kp, vt);
  k_chunkkv<<<dim3(NCH, HH), blk, 0, stream>>>(kp, vt, kvt, ksum);
  k_prefix<<<dim3(16, HH), blk, 0, stream>>>(kvt, ksum, st, zf);
  k_attn<<<dim3(NCH, HH), blk, 0, stream>>>(qp, kp, vt, st, zf, attnb);
  k_out_mfma<<<dim3(CC / 64, TT / 64), blk, 0, stream>>>(attnb, woT, b_out, out);
}

// Round 10
// 68.905 us; speedup vs baseline: 1.3710x; 1.0002x over previous
//
#include <hip/hip_runtime.h>
#include <hip/hip_bf16.h>

#define TT 2048
#define CC 1024
#define HH 16
#define DD 64
#define FM 64
#define NCH 32
#define CL 64
#define N_QKV 3072
#define EPSV 1e-6f

// fp32 workspace region (float units)
#define OFF_KS  0u          // Ksum fp32 [16][32][64m]
#define OFF_Z   32768u      // z fp32 [16][32][64m]
#define OFF_U16 65536u      // bf16 region start (float units)
// bf16 region offsets (ushort units)
#define U_KVT 0u            // KV^T bf16 [16][32][64d][64m]
#define U_PROJT 2097152u    // projT bf16 [16][64m][64d]
#define U_VT  6291456u      // v^T bf16 [16][64][2048]
#define U_QP  8388608u      // q' bf16 [16][2048][64m]
#define U_KP  10485760u     // k' bf16 [16][2048][64m]
#define U_ST  12582912u     // S^T bf16 [16][32][64d][64m]
#define U_XBF 14680064u     // x bf16 (later aliased as attnb)
#define U_WQT 16777216u     // w_qkv^T bf16 [3072][1024]
#define U_WOT 19922944u     // w_out^T bf16 [1024][1024]

typedef __attribute__((ext_vector_type(8))) short bf16x8;
typedef __attribute__((ext_vector_type(4))) float f32x4;
typedef __attribute__((ext_vector_type(4))) unsigned short u16x4;

__device__ __forceinline__ unsigned short f2bf(float f) {
  unsigned int u = __float_as_uint(f);
  u = (u + 0x7fffu + ((u >> 16) & 1u)) >> 16;
  return (unsigned short)u;
}
__device__ __forceinline__ float bf2f(unsigned short b) {
  return __uint_as_float(((unsigned)b) << 16);
}

__device__ __forceinline__ void gload16(const void* g, void* l) {
  __builtin_amdgcn_global_load_lds(
      (const __attribute__((address_space(1))) unsigned int*)g,
      (__attribute__((address_space(3))) unsigned int*)l, 16, 0, 0);
}

// stage a 64-row x 64-ushort (8KB) tile into LDS, XOR-swizzled (chunk^=row&7)
__device__ __forceinline__ void stage_tile64(const unsigned short* g, unsigned rowstride,
                                             unsigned short* lds, int w, int lane) {
  const int l8 = lane >> 3, l7 = lane & 7;
  const int kcg = (l7 ^ l8) * 8;
#pragma unroll
  for (int jj = 0; jj < 2; ++jj) {
    const int inst = w * 2 + jj;
    const int row = inst * 8 + l8;
    gload16(&g[(unsigned)row * rowstride + kcg], &lds[inst * 512]);
  }
}

// read an 8-element bf16 fragment from a swizzled 64x64 LDS tile
__device__ __forceinline__ bf16x8 frag64(const unsigned short* lds, int r, int kchunk) {
  const int slot = kchunk ^ (r & 7);
  return *reinterpret_cast<const bf16x8*>(&lds[r * 64 + slot * 8]);
}

// ---------------- Kernel 0: fused prep (xconv + transposes + projT) --------
__device__ __forceinline__ void transpose64_dev(const float* __restrict__ src,
                                                unsigned short* __restrict__ dst,
                                                int K, int N, int k0, int n0,
                                                float (*T)[68], int tid) {
#pragma unroll
  for (int it = 0; it < 4; ++it) {
    int f = tid + it * 256;
    int r = f >> 4, c4 = (f & 15) * 4;
    float4 v = *reinterpret_cast<const float4*>(&src[(unsigned)(k0 + r) * N + n0 + c4]);
    T[r][c4 + 0] = v.x; T[r][c4 + 1] = v.y;
    T[r][c4 + 2] = v.z; T[r][c4 + 3] = v.w;
  }
  __syncthreads();
#pragma unroll
  for (int it = 0; it < 4; ++it) {
    int f = tid + it * 256;
    int nl = f >> 4, kq = (f & 15) * 4;
    u16x4 o;
#pragma unroll
    for (int j = 0; j < 4; ++j) o[j] = f2bf(T[kq + j][nl]);
    *reinterpret_cast<u16x4*>(&dst[(unsigned)(n0 + nl) * K + k0 + kq]) = o;
  }
}

__global__ __launch_bounds__(256) void k_prep(const float* __restrict__ x,
                                              const float* __restrict__ wq,
                                              const float* __restrict__ wo,
                                              const float* __restrict__ proj,
                                              unsigned short* __restrict__ xbf,
                                              unsigned short* __restrict__ wqT,
                                              unsigned short* __restrict__ woT,
                                              unsigned short* __restrict__ projT) {
  __shared__ float T[64][68];
  const int tid = threadIdx.x;
  int b = blockIdx.x;
  if (b < 2048) {  // x f32 -> bf16
    unsigned i = (unsigned)b * 1024u + (unsigned)tid * 4u;
    float4 v = *reinterpret_cast<const float4*>(&x[i]);
    u16x4 o;
    o[0] = f2bf(v.x); o[1] = f2bf(v.y); o[2] = f2bf(v.z); o[3] = f2bf(v.w);
    *reinterpret_cast<u16x4*>(&xbf[i]) = o;
    return;
  }
  b -= 2048;
  if (b < 768) {  // w_qkv [1024][3072] -> wqT [3072][1024]
    transpose64_dev(wq, wqT, CC, N_QKV, (b / 48) * 64, (b % 48) * 64, T, tid);
    return;
  }
  b -= 768;
  if (b < 256) {  // w_out [1024][1024] -> woT [1024][1024]
    transpose64_dev(wo, woT, CC, CC, (b / 16) * 64, (b % 16) * 64, T, tid);
    return;
  }
  b -= 256;  // proj [h][64d][64m] -> projT [h][64m][64d]
  transpose64_dev(proj + (unsigned)b * 4096u, projT + (unsigned)b * 4096u, 64, 64, 0, 0, T, tid);
}

// ---------------- Kernel 1: qkv GEMM + fused feature map (BK=128 dbuf) -----
// q/k warps: p' = relu(tile @ projT)/8 computed in-epilogue -> qp/kp [h][t][m]
// v warps: vT bf16 [h][d][t]
__global__ __launch_bounds__(256) void k_qkv_mfma(const unsigned short* __restrict__ Xbf,
                                                  const unsigned short* __restrict__ WqT,
                                                  const float* __restrict__ bias,
                                                  const unsigned short* __restrict__ projT,
                                                  unsigned short* __restrict__ qp,
                                                  unsigned short* __restrict__ kp,
                                                  unsigned short* __restrict__ vt) {
  // As0@0 As1@4096 | Bs0@8192 Bs1@16384  (48 KB total)
  __shared__ unsigned short LDSU[24576];
  const int tid = threadIdx.x, lane = tid & 63, w = tid >> 6;
  const int wm = w >> 1, wn = w & 1;   // 2M x 2N warp layout (32 x 64 per warp)
  // XCD-aware bijective swizzle: nwg = 24*32 = 768, 768%8==0, cpx=96
  int lin = blockIdx.y * 24 + blockIdx.x;
  int swz = (lin & 7) * 96 + (lin >> 3);
  const int bx = swz % 24, by = swz / 24;
  const int m0b = by * 64, n0b = bx * 128;
  const int l8 = lane >> 3, l7 = lane & 7;
  const int kcg = (l7 ^ l8) * 8;
  f32x4 acc[2][4] = {};
  for (int k0 = 0; k0 < CC; k0 += 128) {
    if (k0) __syncthreads();
#pragma unroll
    for (int half = 0; half < 2; ++half) {
      unsigned short* Asb = LDSU + half * 4096;
      unsigned short* Bsb = LDSU + 8192 + half * 8192;
      const int kh = k0 + half * 64;
#pragma unroll
      for (int jj = 0; jj < 2; ++jj) {   // A: 64x64
        const int inst = w * 2 + jj;
        const int row = inst * 8 + l8;
        gload16(&Xbf[(unsigned)(m0b + row) * CC + kh + kcg], &Asb[inst * 512]);
      }
#pragma unroll
      for (int jj = 0; jj < 4; ++jj) {   // B: 128x64
        const int inst = w * 4 + jj;
        const int row = inst * 8 + l8;
        gload16(&WqT[(unsigned)(n0b + row) * CC + kh + kcg], &Bsb[inst * 512]);
      }
    }
    __syncthreads();
#pragma unroll
    for (int half = 0; half < 2; ++half) {
      const unsigned short* Asb = LDSU + half * 4096;
      const unsigned short* Bsb = LDSU + 8192 + half * 8192;
#pragma unroll
      for (int kk = 0; kk < 2; ++kk) {
        bf16x8 af[2], bg[4];
#pragma unroll
        for (int i = 0; i < 2; ++i) {
          const int r = wm * 32 + i * 16 + (lane & 15);
          const int slot = (kk * 4 + (lane >> 4)) ^ (r & 7);
          af[i] = *reinterpret_cast<const bf16x8*>(&Asb[r * 64 + slot * 8]);
        }
#pragma unroll
        for (int j = 0; j < 4; ++j) {
          const int r = wn * 64 + j * 16 + (lane & 15);
          const int slot = (kk * 4 + (lane >> 4)) ^ (r & 7);
          bg[j] = *reinterpret_cast<const bf16x8*>(&Bsb[r * 64 + slot * 8]);
        }
#pragma unroll
        for (int i = 0; i < 2; ++i)
#pragma unroll
          for (int j = 0; j < 4; ++j)
            acc[i][j] = __builtin_amdgcn_mfma_f32_16x16x32_bf16(af[i], bg[j],
                                                                acc[i][j], 0, 0, 0);
      }
    }
  }
  const int n0w = n0b + wn * 64;       // one (sel,h) per warp (block-uniform sel)
  const int sel = n0w >> 10;
  const int h = (n0w & 1023) >> 6;
  const int t0w = m0b + wm * 32;
  float bvj[4];
#pragma unroll
  for (int j = 0; j < 4; ++j) bvj[j] = bias[n0w + j * 16 + (lane & 15)];
  __syncthreads();  // all MFMA reads of LDSU done
  // stage warp's 32t x 64d tile (+bias, bf16) into private quadrant, swizzled
  unsigned short* myT = LDSU + w * 2048;
#pragma unroll
  for (int i = 0; i < 2; ++i)
#pragma unroll
    for (int j = 0; j < 4; ++j) {
      const int d = j * 16 + (lane & 15);
#pragma unroll
      for (int r = 0; r < 4; ++r) {
        const int t = i * 16 + (lane >> 4) * 4 + r;
        myT[t * 64 + (((d >> 3) ^ (t & 7)) << 3) + (d & 7)] = f2bf(acc[i][j][r] + bvj[j]);
      }
    }
  if (sel == 2) {
    // vT [h][d][t]: per lane 4x bf16x8 along t (64B-line writes)
#pragma unroll
    for (int q = 0; q < 4; ++q) {
      const int cid = q * 64 + lane;
      const int d = cid >> 2, tc = cid & 3;
      bf16x8 o;
#pragma unroll
      for (int e = 0; e < 8; ++e) {
        const int t = tc * 8 + e;
        o[e] = (short)myT[t * 64 + (((d >> 3) ^ (t & 7)) << 3) + (d & 7)];
      }
      *reinterpret_cast<bf16x8*>(&vt[((unsigned)h * 64 + d) * TT + t0w + tc * 8]) = o;
    }
    return;
  }
  // fused feature map: p'[t][m] = relu(sum_d tile[t][d] projT[h][m][d]) / 8
  const unsigned short* pjt = projT + (unsigned)h * 4096u;
  bf16x8 aq[2][2], bp[4][2];
#pragma unroll
  for (int jm = 0; jm < 4; ++jm)
#pragma unroll
    for (int kk = 0; kk < 2; ++kk)
      bp[jm][kk] = *reinterpret_cast<const bf16x8*>(
          &pjt[(unsigned)(jm * 16 + (lane & 15)) * 64 + kk * 32 + (lane >> 4) * 8]);
#pragma unroll
  for (int i = 0; i < 2; ++i)
#pragma unroll
    for (int kk = 0; kk < 2; ++kk)
      aq[i][kk] = frag64(myT, i * 16 + (lane & 15), kk * 4 + (lane >> 4));
  f32x4 accp[2][4] = {};
#pragma unroll
  for (int i = 0; i < 2; ++i)
#pragma unroll
    for (int jm = 0; jm < 4; ++jm)
#pragma unroll
      for (int kk = 0; kk < 2; ++kk)
        accp[i][jm] = __builtin_amdgcn_mfma_f32_16x16x32_bf16(aq[i][kk], bp[jm][kk],
                                                              accp[i][jm], 0, 0, 0);
  // relu/8 + restage p' into myT as [t][m] swizzled (warp-private, in-order DS)
#pragma unroll
  for (int i = 0; i < 2; ++i)
#pragma unroll
    for (int jm = 0; jm < 4; ++jm) {
      const int m = jm * 16 + (lane & 15);
#pragma unroll
      for (int r = 0; r < 4; ++r) {
        const int t = i * 16 + (lane >> 4) * 4 + r;
        float v = accp[i][jm][r];
        v = (v > 0.f ? v : 0.f) * 0.125f;
        myT[t * 64 + (((m >> 3) ^ (t & 7)) << 3) + (m & 7)] = f2bf(v);
      }
    }
  // coalesced store: q'/k' [h][t][m], 1KB per store instruction
  unsigned short* dst0 = (sel ? kp : qp) + ((unsigned)h * TT + (unsigned)t0w) * 64u;
#pragma unroll
  for (int q = 0; q < 4; ++q) {
    const int cid = q * 64 + lane;
    const int t = cid >> 3, mc = cid & 7;
    bf16x8 o = *reinterpret_cast<const bf16x8*>(&myT[t * 64 + ((mc ^ (t & 7)) << 3)]);
    *reinterpret_cast<bf16x8*>(&dst0[(unsigned)cid * 8]) = o;
  }
}

// ---------------- Kernel 2: per-chunk KV^T[d][m] + Ksum (MFMA) -------------
__global__ __launch_bounds__(256) void k_chunkkv(const unsigned short* __restrict__ kp,
                                                 const unsigned short* __restrict__ vt,
                                                 unsigned short* __restrict__ kvt,
                                                 float* __restrict__ ksum) {
  __shared__ unsigned short Xs[4096];
  __shared__ unsigned short VTs[4096];
  const int tid = threadIdx.x, lane = tid & 63, w = tid >> 6;
  const int c = blockIdx.x, h = blockIdx.y;
  stage_tile64(kp + ((unsigned)h * TT + c * 64) * 64, 64, Xs, w, lane);
  stage_tile64(vt + (unsigned)h * 64 * TT + (unsigned)c * 64, TT, VTs, w, lane);
  __syncthreads();
  // A-frags (rows m, k=t) gathered from swizzled Xs [t][m]
  const int m = w * 16 + (lane & 15);
  bf16x8 afm[2];
  float ks = 0.f;
#pragma unroll
  for (int kk = 0; kk < 2; ++kk)
#pragma unroll
    for (int e = 0; e < 8; ++e) {
      const int t = kk * 32 + (lane >> 4) * 8 + e;
      unsigned short u = Xs[t * 64 + (((m >> 3) ^ (t & 7)) << 3) + (m & 7)];
      afm[kk][e] = (short)u;
      ks += bf2f(u);
    }
  ks += __shfl_xor(ks, 16, 64);
  ks += __shfl_xor(ks, 32, 64);
  if (lane < 16) ksum[((unsigned)h * NCH + c) * 64u + m] = ks;
  f32x4 acckv[4] = {};
#pragma unroll
  for (int j = 0; j < 4; ++j)
#pragma unroll
    for (int kk = 0; kk < 2; ++kk)
      acckv[j] = __builtin_amdgcn_mfma_f32_16x16x32_bf16(
          afm[kk], frag64(VTs, j * 16 + (lane & 15), kk * 4 + (lane >> 4)), acckv[j], 0, 0, 0);
  unsigned short* dkv = kvt + ((unsigned)h * NCH + c) * 4096u;
#pragma unroll
  for (int j = 0; j < 4; ++j) {
    const int d = j * 16 + (lane & 15);
    const int mq = w * 16 + (lane >> 4) * 4;
    u16x4 o;
#pragma unroll
    for (int r = 0; r < 4; ++r) o[r] = f2bf(acckv[j][r]);
    *reinterpret_cast<u16x4*>(&dkv[(unsigned)d * 64 + mq]) = o;
  }
}

// ---------------- Kernel 4: exclusive prefix over chunks (parallel) --------
__global__ __launch_bounds__(256) void k_prefix(const unsigned short* __restrict__ kvt,
                                                const float* __restrict__ ksum,
                                                unsigned short* __restrict__ st,
                                                float* __restrict__ z) {
  const int h = blockIdx.y;
  const unsigned e = blockIdx.x * 256u + threadIdx.x;
  float run = 0.f;
#pragma unroll
  for (int c = 0; c < NCH; ++c) {
    const unsigned idx = ((unsigned)h * NCH + c) * 4096u + e;
    st[idx] = f2bf(run);
    run += bf2f(kvt[idx]);
  }
  if (blockIdx.x == 0 && threadIdx.x < 64) {
    float zr = 0.f;
#pragma unroll
    for (int c = 0; c < NCH; ++c) {
      const unsigned idx = ((unsigned)h * NCH + c) * 64u + threadIdx.x;
      z[idx] = zr;
      zr += ksum[idx];
    }
  }
}

// ---------------- Kernel 5: per-(h,c) intra-chunk attention (MFMA) ---------
__global__ __launch_bounds__(256) void k_attn(const unsigned short* __restrict__ qp,
                                              const unsigned short* __restrict__ kp,
                                              const unsigned short* __restrict__ vt,
                                              const unsigned short* __restrict__ st,
                                              const float* __restrict__ z,
                                              unsigned short* __restrict__ attnb) {
  __shared__ unsigned short QPs[4096];  // reused as ctx bf16 at epilogue
  __shared__ unsigned short KPs[4096];  // reused as A^bf16 after phase A
  __shared__ unsigned short VTs[4096];
  __shared__ unsigned short STs[4096];
  __shared__ float zsm[64];
  __shared__ float nsm[64];
  const int tid = threadIdx.x, lane = tid & 63, w = tid >> 6;
  const int c = blockIdx.x, h = blockIdx.y;
  stage_tile64(qp + ((unsigned)h * TT + c * 64) * 64, 64, QPs, w, lane);
  stage_tile64(kp + ((unsigned)h * TT + c * 64) * 64, 64, KPs, w, lane);
  stage_tile64(vt + (unsigned)h * 64 * TT + (unsigned)c * 64, TT, VTs, w, lane);
  stage_tile64(st + ((unsigned)h * NCH + c) * 4096u, 64, STs, w, lane);
  if (tid < 64) zsm[tid] = z[((unsigned)h * NCH + c) * 64u + tid];
  __syncthreads();
  const int tr = w * 16 + (lane & 15);
  bf16x8 afq[2];
#pragma unroll
  for (int kk = 0; kk < 2; ++kk) afq[kk] = frag64(QPs, tr, kk * 4 + (lane >> 4));
  f32x4 accA[4] = {};
#pragma unroll
  for (int j = 0; j < 4; ++j)
#pragma unroll
    for (int kk = 0; kk < 2; ++kk)
      accA[j] = __builtin_amdgcn_mfma_f32_16x16x32_bf16(
          afq[kk], frag64(KPs, j * 16 + (lane & 15), kk * 4 + (lane >> 4)), accA[j], 0, 0, 0);
  float rs[4] = {0.f, 0.f, 0.f, 0.f};
#pragma unroll
  for (int j = 0; j < 4; ++j) {
    const int s = j * 16 + (lane & 15);
#pragma unroll
    for (int r = 0; r < 4; ++r) {
      const int t = w * 16 + (lane >> 4) * 4 + r;
      float v = (s <= t) ? accA[j][r] : 0.f;
      accA[j][r] = v;
      rs[r] += v;
    }
  }
#pragma unroll
  for (int r = 0; r < 4; ++r)
#pragma unroll
    for (int off = 1; off < 16; off <<= 1) rs[r] += __shfl_xor(rs[r], off, 64);
  __syncthreads();
  if ((lane & 15) == 0) {
#pragma unroll
    for (int r = 0; r < 4; ++r) nsm[w * 16 + (lane >> 4) * 4 + r] = rs[r];
  }
#pragma unroll
  for (int j = 0; j < 4; ++j) {
    const int s = j * 16 + (lane & 15);
#pragma unroll
    for (int r = 0; r < 4; ++r) {
      const int t = w * 16 + (lane >> 4) * 4 + r;
      KPs[t * 64 + (((s >> 3) ^ (t & 7)) * 8) + (s & 7)] = f2bf(accA[j][r]);
    }
  }
  __syncthreads();
  {
    const int t = tid >> 2, part = tid & 3;
    float qz = 0.f;
#pragma unroll
    for (int mm = 0; mm < 16; ++mm) {
      const int m = part * 16 + mm;
      qz += bf2f(QPs[t * 64 + (((m >> 3) ^ (t & 7)) * 8) + (m & 7)]) * zsm[m];
    }
    qz += __shfl_xor(qz, 1, 64);
    qz += __shfl_xor(qz, 2, 64);
    if (part == 0) nsm[t] += qz + EPSV;
  }
  bf16x8 afa[2];
#pragma unroll
  for (int kk = 0; kk < 2; ++kk) afa[kk] = frag64(KPs, tr, kk * 4 + (lane >> 4));
  f32x4 acc[4] = {};
#pragma unroll
  for (int j = 0; j < 4; ++j) {
    const int br = j * 16 + (lane & 15);
#pragma unroll
    for (int kk = 0; kk < 2; ++kk) {
      acc[j] = __builtin_amdgcn_mfma_f32_16x16x32_bf16(
          afa[kk], frag64(VTs, br, kk * 4 + (lane >> 4)), acc[j], 0, 0, 0);
      acc[j] = __builtin_amdgcn_mfma_f32_16x16x32_bf16(
          afq[kk], frag64(STs, br, kk * 4 + (lane >> 4)), acc[j], 0, 0, 0);
    }
  }
  __syncthreads();  // nsm finalized; QPs dead -> reuse for ctx staging
#pragma unroll
  for (int j = 0; j < 4; ++j) {
    const int d = j * 16 + (lane & 15);
#pragma unroll
    for (int r = 0; r < 4; ++r) {
      const int t = w * 16 + (lane >> 4) * 4 + r;
      QPs[t * 64 + (((d >> 3) ^ (t & 7)) << 3) + (d & 7)] = f2bf(acc[j][r] / nsm[t]);
    }
  }
  __syncthreads();
  // coalesced store: 128B-contiguous row segments
  unsigned short* dstA = attnb + (unsigned)(c * 64) * CC + (unsigned)h * 64;
#pragma unroll
  for (int q = 0; q < 2; ++q) {
    const int cid = q * 256 + tid;
    const int t = cid >> 3, dc = cid & 7;
    bf16x8 o = *reinterpret_cast<const bf16x8*>(&QPs[t * 64 + ((dc ^ (t & 7)) << 3)]);
    *reinterpret_cast<bf16x8*>(&dstA[(unsigned)t * CC + dc * 8]) = o;
  }
}

// ---------------- Kernel 6: out = attn @ w_out + b (64x64, BK=128 dbuf) ----
__global__ __launch_bounds__(256) void k_out_mfma(const unsigned short* __restrict__ Abf,
                                                  const unsigned short* __restrict__ WoT,
                                                  const float* __restrict__ bias,
                                                  float* __restrict__ out) {
  // As0@0 As1@4096 Bs0@8192 Bs1@12288  (32 KB total)
  __shared__ unsigned short LDSU[16384];
  const int tid = threadIdx.x, lane = tid & 63, w = tid >> 6;
  const int wm = w >> 1, wn = w & 1;   // 2M x 2N, 32x32 per warp
  // XCD-aware bijective swizzle (nwg = 16*32 = 512, cpx=64)
  int lin = blockIdx.y * 16 + blockIdx.x;
  int swz = (lin & 7) * 64 + (lin >> 3);
  const int bx = swz & 15, by = swz >> 4;
  const int m0 = by * 64, n0 = bx * 64;
  const int l8 = lane >> 3, l7 = lane & 7;
  const int kcg = (l7 ^ l8) * 8;
  f32x4 acc[2][2] = {};
  for (int k0 = 0; k0 < CC; k0 += 128) {
    if (k0) __syncthreads();
#pragma unroll
    for (int half = 0; half < 2; ++half) {
      unsigned short* Asb = LDSU + half * 4096;
      unsigned short* Bsb = LDSU + 8192 + half * 4096;
      const int kh = k0 + half * 64;
#pragma unroll
      for (int jj = 0; jj < 2; ++jj) {
        const int inst = w * 2 + jj;
        const int row = inst * 8 + l8;
        gload16(&Abf[(unsigned)(m0 + row) * CC + kh + kcg], &Asb[inst * 512]);
        gload16(&WoT[(unsigned)(n0 + row) * CC + kh + kcg], &Bsb[inst * 512]);
      }
    }
    __syncthreads();
#pragma unroll
    for (int half = 0; half < 2; ++half) {
      const unsigned short* Asb = LDSU + half * 4096;
      const unsigned short* Bsb = LDSU + 8192 + half * 4096;
#pragma unroll
      for (int kk = 0; kk < 2; ++kk) {
        bf16x8 af[2], bg[2];
#pragma unroll
        for (int i = 0; i < 2; ++i) {
          const int r = wm * 32 + i * 16 + (lane & 15);
          const int slot = (kk * 4 + (lane >> 4)) ^ (r & 7);
          af[i] = *reinterpret_cast<const bf16x8*>(&Asb[r * 64 + slot * 8]);
        }
#pragma unroll
        for (int j = 0; j < 2; ++j) {
          const int r = wn * 32 + j * 16 + (lane & 15);
          const int slot = (kk * 4 + (lane >> 4)) ^ (r & 7);
          bg[j] = *reinterpret_cast<const bf16x8*>(&Bsb[r * 64 + slot * 8]);
        }
#pragma unroll
        for (int i = 0; i < 2; ++i)
#pragma unroll
          for (int j = 0; j < 2; ++j)
            acc[i][j] = __builtin_amdgcn_mfma_f32_16x16x32_bf16(af[i], bg[j],
                                                                acc[i][j], 0, 0, 0);
      }
    }
  }
#pragma unroll
  for (int i = 0; i < 2; ++i) {
#pragma unroll
    for (int j = 0; j < 2; ++j) {
      const int n = n0 + wn * 32 + j * 16 + (lane & 15);
      const float bv = bias[n];
#pragma unroll
      for (int r = 0; r < 4; ++r) {
        const int m = m0 + wm * 32 + i * 16 + (lane >> 4) * 4 + r;
        out[(unsigned)m * CC + n] = acc[i][j][r] + bv;
      }
    }
  }
}

extern "C" void kernel_launch(void* const* d_in, const int* in_sizes, int n_in,
                              void* d_out, int out_size, void* d_ws, size_t ws_size,
                              hipStream_t stream) {
  const float* x = (const float*)d_in[0];
  const float* w_qkv = (const float*)d_in[1];
  const float* b_qkv = (const float*)d_in[2];
  const float* w_out = (const float*)d_in[3];
  const float* b_out = (const float*)d_in[4];
  const float* proj = (const float*)d_in[5];
  float* ws = (float*)d_ws;
  float* out = (float*)d_out;
  float* ksum = ws + OFF_KS;
  float* zf = ws + OFF_Z;
  unsigned short* ub = (unsigned short*)(ws + OFF_U16);
  unsigned short* kvt = ub + U_KVT;
  unsigned short* projT = ub + U_PROJT;
  unsigned short* vt = ub + U_VT;
  unsigned short* qp = ub + U_QP;
  unsigned short* kp = ub + U_KP;
  unsigned short* st = ub + U_ST;
  unsigned short* xbf = ub + U_XBF;
  unsigned short* wqT = ub + U_WQT;
  unsigned short* woT = ub + U_WOT;
  unsigned short* attnb = xbf;  // alias: x_bf16 dead after k_qkv_mfma
  dim3 blk(256, 1, 1);
  k_prep<<<dim3(3088), blk, 0, stream>>>(x, w_qkv, w_out, proj, xbf, wqT, woT, projT);
  k_qkv_mfma<<<dim3(N_QKV / 128, TT / 64), blk, 0, stream>>>(xbf, wqT, b_qkv, projT,
                                                             qp, kp, vt);
  k_chunkkv<<<dim3(NCH, HH), blk, 0, stream>>>(kp, vt, kvt, ksum);
  k_prefix<<<dim3(16, HH), blk, 0, stream>>>(kvt, ksum, st, zf);
  k_attn<<<dim3(NCH, HH), blk, 0, stream>>>(qp, kp, vt, st, zf, attnb);
  k_out_mfma<<<dim3(CC / 64, TT / 64), blk, 0, stream>>>(attnb, woT, b_out, out);
}